// Round 8
// baseline (652.676 us; speedup 1.0000x reference)
//
#include <hip/hip_runtime.h>
#include <hip/hip_bf16.h>

#define N_NODES 10000
#define N_EDGES 160000

// ===========================================================================
// CG tensor computation (device-side, validated round 1)
// ===========================================================================
static __device__ const int CG_COMBOS[15][4] = {
  {0,0,0,0},{0,1,1,1},{0,2,2,10},{1,0,1,35},{1,1,0,44},{1,1,1,53},{1,1,2,80},
  {1,2,1,125},{1,2,2,170},{2,0,2,245},{2,1,1,270},{2,1,2,315},{2,2,0,390},
  {2,2,1,415},{2,2,2,490}
};

__device__ inline double factd(int n){ double f=1.0; for(int i=2;i<=n;i++) f*=(double)i; return f; }

__device__ double cg_complex_dev(int j1,int m1,int j2,int m2,int j3,int m3){
  if (m1+m2 != m3) return 0.0;
  double pref = sqrt((2.0*j3+1.0)*factd(j1+j2-j3)*factd(j1-j2+j3)*factd(-j1+j2+j3)/factd(j1+j2+j3+1));
  pref *= sqrt(factd(j1+m1)*factd(j1-m1)*factd(j2+m2)*factd(j2-m2)*factd(j3+m3)*factd(j3-m3));
  int kmin = 0; if (j2-j3-m1 > kmin) kmin = j2-j3-m1; if (j1-j3+m2 > kmin) kmin = j1-j3+m2;
  int kmax = j1+j2-j3; if (j1-m1 < kmax) kmax = j1-m1; if (j2+m2 < kmax) kmax = j2+m2;
  double s = 0.0;
  for (int k=kmin; k<=kmax; ++k){
    double d = factd(k)*factd(j1+j2-j3-k)*factd(j1-m1-k)*factd(j2+m2-k)*factd(j3-j2+m1+k)*factd(j3-j1-m2+k);
    s += ((k&1) ? -1.0 : 1.0)/d;
  }
  return pref*s;
}

__device__ inline void q_elem(int l, int r, int c, double* re, double* im){
  const double s2 = 0.7071067811865476;
  *re = 0.0; *im = 0.0;
  int mr = r - l, mc = c - l;
  if (mr == 0){ if (mc == 0) *re = 1.0; return; }
  if (mr > 0){
    int m = mr;
    if (mc == m)       *re = (m&1) ? -s2 : s2;
    else if (mc == -m) *re = s2;
  } else {
    int m = -mr;
    if (mc == -m)      *im = s2;
    else if (mc == m)  *im = (m&1) ? s2 : -s2;
  }
}

__global__ __launch_bounds__(128) void cg_init_kernel(float* __restrict__ cgbuf){
  __shared__ double Cr[125], Ci[125];
  __shared__ double Qr[3][25], Qi[3][25];
  __shared__ double Kr[125], Ki[125];
  __shared__ double red[128];
  int t = threadIdx.x, b = blockIdx.x;
  int l1 = CG_COMBOS[b][0], l2 = CG_COMBOS[b][1], l3 = CG_COMBOS[b][2], off = CG_COMBOS[b][3];
  int n1 = 2*l1+1, n2 = 2*l2+1, n3 = 2*l3+1;
  int tot = n1*n2*n3;
  for (int i=t; i<tot; i+=128){ Cr[i]=0.0; Ci[i]=0.0; }
  __syncthreads();
  if (t < n1*n2){
    int m1 = t/n2 - l1, m2 = t%n2 - l2, m3 = m1+m2;
    if (m3 >= -l3 && m3 <= l3)
      Cr[t*n3 + (l3+m3)] = cg_complex_dev(l1,m1,l2,m2,l3,m3);
  }
  int ls[3] = {l1,l2,l3};
  for (int q=0;q<3;q++){
    int n = 2*ls[q]+1;
    if (t < n*n) q_elem(ls[q], t/n, t%n, &Qr[q][t], &Qi[q][t]);
  }
  __syncthreads();
  if (t < tot){
    int i = t/(n2*n3), j = (t/n3)%n2, k = t%n3;
    double sr=0.0, si=0.0;
    for (int a=0;a<n1;a++){
      double q1r = Qr[0][i*n1+a], q1i = -Qi[0][i*n1+a];
      for (int bb=0;bb<n2;bb++){
        double q2r = Qr[1][j*n2+bb], q2i = -Qi[1][j*n2+bb];
        double pr = q1r*q2r - q1i*q2i, pi = q1r*q2i + q1i*q2r;
        for (int c=0;c<n3;c++){
          double cr = Cr[(a*n2+bb)*n3+c], ci = Ci[(a*n2+bb)*n3+c];
          if (cr==0.0 && ci==0.0) continue;
          double q3r = Qr[2][k*n3+c], q3i = Qi[2][k*n3+c];
          double tr = pr*q3r - pi*q3i, ti = pr*q3i + pi*q3r;
          sr += tr*cr - ti*ci;
          si += tr*ci + ti*cr;
        }
      }
    }
    Kr[t]=sr; Ki[t]=si;
  }
  __syncthreads();
  double v = (t<tot) ? fabs(Kr[t]) : 0.0;
  red[t]=v; __syncthreads();
  for (int s=64;s>0;s>>=1){ if (t<s && red[t+s]>red[t]) red[t]=red[t+s]; __syncthreads(); }
  double maxRe = red[0]; __syncthreads();
  v = (t<tot) ? fabs(Ki[t]) : 0.0;
  red[t]=v; __syncthreads();
  for (int s=64;s>0;s>>=1){ if (t<s && red[t+s]>red[t]) red[t]=red[t+s]; __syncthreads(); }
  double maxIm = red[0]; __syncthreads();
  bool useIm = (maxIm > maxRe);
  double pick = (t<tot) ? (useIm ? -Ki[t] : Kr[t]) : 0.0;
  red[t] = pick*pick; __syncthreads();
  for (int s=64;s>0;s>>=1){ if (t<s) red[t]+=red[t+s]; __syncthreads(); }
  double scale = sqrt((double)n3) / sqrt(red[0]);
  if (t<tot) cgbuf[off+t] = (float)(pick*scale);
}

// ===========================================================================
// CSR build + degree-descending node permutation (load balance)
// ===========================================================================
__global__ void hist_kernel(const int* __restrict__ dst, int* __restrict__ deg){
  int e = blockIdx.x*256 + threadIdx.x;
  atomicAdd(&deg[dst[e]], 1);
}

__global__ __launch_bounds__(1024) void scan_kernel(const int* __restrict__ deg,
                                                    int* __restrict__ offs,
                                                    int* __restrict__ cursor){
  __shared__ int lds[1024];
  __shared__ int run_s;
  int tid = threadIdx.x;
  if (tid==0) run_s = 0;
  __syncthreads();
  for (int base=0; base<N_NODES; base+=1024){
    int i = base + tid;
    int vv = (i<N_NODES) ? deg[i] : 0;
    lds[tid]=vv; __syncthreads();
    for (int off=1; off<1024; off<<=1){
      int a = lds[tid];
      int b = (tid>=off) ? lds[tid-off] : 0;
      __syncthreads();
      lds[tid] = a + b;
      __syncthreads();
    }
    int incl = lds[tid];
    int run = run_s;
    if (i < N_NODES){ int ex = run + incl - vv; offs[i]=ex; cursor[i]=ex; }
    __syncthreads();
    if (tid==1023) run_s = run + lds[1023];
    __syncthreads();
  }
  if (tid==0) offs[N_NODES] = run_s;
}

__global__ void scatter_kernel(const int* __restrict__ dst, int* __restrict__ cursor,
                               int* __restrict__ eids, int* __restrict__ pos){
  int e = blockIdx.x*256 + threadIdx.x;
  int p = atomicAdd(&cursor[dst[e]], 1);
  eids[p] = e;
  pos[e] = p;
}

__global__ void perm_kernel(const int* __restrict__ eids, const int* __restrict__ edge_src,
                            const float* __restrict__ edge_vec,
                            int* __restrict__ src_perm, float* __restrict__ vec_perm){
  int p = blockIdx.x*256 + threadIdx.x;
  int e = eids[p];
  src_perm[p] = edge_src[e];
  vec_perm[3*p]   = edge_vec[3*e];
  vec_perm[3*p+1] = edge_vec[3*e+1];
  vec_perm[3*p+2] = edge_vec[3*e+2];
}

// degree-descending counting sort of nodes (64 bins)
__global__ void dhist_kernel(const int* __restrict__ deg, int* __restrict__ dhist){
  int i = blockIdx.x*256 + threadIdx.x;
  if (i < N_NODES){
    int d = deg[i]; if (d > 63) d = 63;
    atomicAdd(&dhist[63-d], 1);
  }
}
__global__ __launch_bounds__(64) void dscan_kernel(const int* __restrict__ dhist,
                                                   int* __restrict__ dcur){
  if (threadIdx.x==0){
    int run = 0;
    for (int b=0;b<64;b++){ dcur[b] = run; run += dhist[b]; }
  }
}
__global__ void dscatter_kernel(const int* __restrict__ deg, int* __restrict__ dcur,
                                int* __restrict__ nodeperm){
  int i = blockIdx.x*256 + threadIdx.x;
  if (i < N_NODES){
    int d = deg[i]; if (d > 63) d = 63;
    int p = atomicAdd(&dcur[63-d], 1);
    nodeperm[p] = i;
  }
}

// ===========================================================================
// Per-edge radial MLP (unchanged, writes pw in CSR order)
// ===========================================================================
template<int WOUT, int WST>
__global__ __launch_bounds__(256) void mlp_kernel(const float* __restrict__ edge_vec,
    const float* __restrict__ w1, const float* __restrict__ w2,
    const int* __restrict__ pos, float* __restrict__ pw){
  __shared__ __align__(16) float emb_s[64*10];
  __shared__ __align__(16) float hid_s[100*64];
  __shared__ int pos_s[64];
  int t = threadIdx.x;
  int eb = blockIdx.x*64;
  if (t < 64){
    int e = eb + t;
    pos_s[t] = pos[e];
    float vx = edge_vec[3*e], vy = edge_vec[3*e+1], vz = edge_vec[3*e+2];
    float r = sqrtf(vx*vx + vy*vy + vz*vz);
    const float EMBC = 1.14136f * 7.3890560989306495f * 3.1622776601683795f;
    #pragma unroll
    for (int bb=0; bb<10; bb++){
      float c = 5.0f*(float)(bb+1)/11.0f;
      float d = (r - c) * (11.0f/5.0f);
      float t1 = d + 1.0f, t2 = 1.0f - d;
      float u1 = (t1 > 0.0f) ? __expf(-1.0f/t1) : 0.0f;
      float u2 = (t2 > 0.0f) ? __expf(-1.0f/t2) : 0.0f;
      emb_s[t*10+bb] = EMBC*u1*u2;
    }
  }
  __syncthreads();
  {
    int e = t & 63, h0 = t >> 6;
    int col = ((e&3)<<4) | (e>>2);
    #pragma unroll
    for (int k=0;k<25;k++){
      int h = h0 + 4*k;
      float s = 0.f;
      #pragma unroll
      for (int bb=0;bb<10;bb++) s += emb_s[e*10+bb]*w1[bb*100+h];
      hid_s[h*64+col] = s/(1.0f+__expf(-s));
    }
  }
  __syncthreads();
  constexpr int NQ = (WOUT+63)/64;
  int cq = t & 63, eg = t >> 6;
  float acc[NQ][16];
  #pragma unroll
  for (int q=0;q<NQ;q++)
    #pragma unroll
    for (int m=0;m<16;m++) acc[q][m]=0.f;
  for (int h=0; h<100; h++){
    float wv[NQ];
    #pragma unroll
    for (int q=0;q<NQ;q++){ int c = cq + 64*q; wv[q] = (c<WOUT) ? w2[h*WOUT+c] : 0.f; }
    const float4* hp = (const float4*)&hid_s[h*64 + (eg<<4)];
    float4 ha = hp[0], hb = hp[1], hc = hp[2], hd = hp[3];
    float hv[16] = {ha.x,ha.y,ha.z,ha.w, hb.x,hb.y,hb.z,hb.w,
                    hc.x,hc.y,hc.z,hc.w, hd.x,hd.y,hd.z,hd.w};
    #pragma unroll
    for (int m=0;m<16;m++){
      #pragma unroll
      for (int q=0;q<NQ;q++) acc[q][m] += wv[q]*hv[m];
    }
  }
  #pragma unroll
  for (int m=0;m<16;m++){
    int row = pos_s[eg + 4*m];
    #pragma unroll
    for (int q=0;q<NQ;q++){
      int c = cq + 64*q;
      if (c < WOUT) pw[(size_t)row*WST + c] = acc[q][m];
    }
  }
}

// ===========================================================================
// Conv: 4 nodes per 256-thread block (degree-matched via nodeperm), one wave
// per node, private LDS/wave. Wave-synchronous. (round-5 structure)
// ===========================================================================
#define WAVE_SYNC() asm volatile("s_waitcnt lgkmcnt(0)" ::: "memory")

// Padded G-layout path tables: {base, alloc, S, ni, nk, nj, yb, cgoff}
static __device__ const short GP1[3][8] = {
  {0,4,1,1,1,1,0,0},{4,4,4,1,3,3,1,1},{8,8,8,1,5,5,4,10}
};
static __device__ const short GP3[3][8] = {
  {0,8,1,1,1,1,0,0},{8,8,1,3,1,3,1,44},{16,8,1,5,1,5,4,390}
};
static __device__ const short GP2[15][8] = {
  {0,4,1,1,1,1,0,0},     // p000
  {4,4,4,1,3,3,1,1},     // p011
  {8,8,8,1,5,5,4,10},    // p022
  {16,12,4,3,3,1,0,35},  // p101
  {28,4,1,3,1,3,1,44},   // p110
  {32,12,4,3,3,3,1,53},  // p111
  {44,24,8,3,5,3,1,80},  // p112
  {68,12,4,3,3,5,4,125}, // p121
  {80,24,8,3,5,5,4,170}, // p122
  {104,40,8,5,5,1,0,245},// p202
  {144,20,4,5,3,3,1,270},// p211
  {164,40,8,5,5,3,1,315},// p212
  {204,8,1,5,1,5,4,390}, // p220
  {212,20,4,5,3,5,4,415},// p221
  {232,40,8,5,5,5,4,490} // p222
};

// Layer-2 msg-round subseg table: [round][sub] = {lo, hi, woff, fcls, gbase}
static __device__ const short L2RS[9][3][5] = {
  {{0,32,  0,0,  0},{0,0,0,0,0},{0,0,0,0,0}},   // r0 <1,1> p000
  {{0,32, 32,0,  4},{0,0,0,0,0},{0,0,0,0,0}},   // r1 <1,3> p011
  {{0,32, 64,0,  8},{0,0,0,0,0},{0,0,0,0,0}},   // r2 <1,5> p022
  {{0,16,112,1, 28},{0,0,0,0,0},{0,0,0,0,0}},   // r3 <3,1> p110
  {{0,16, 96,1, 16},{16,32,128,1,32},{32,48,160,1,68}},  // r4 <3,3> p101,p111,p121
  {{0,16,144,1, 44},{16,32,176,1,80},{0,0,0,0,0}},       // r5 <3,5> p112,p122
  {{0,10,222,2,204},{0,0,0,0,0},{0,0,0,0,0}},   // r6 <5,1> p220
  {{0,10,202,2,144},{10,20,232,2,212},{0,0,0,0,0}},      // r7 <5,3> p211,p221
  {{0,10,192,2,104},{10,20,212,2,164},{20,30,242,2,232}} // r8 <5,5> p202,p212,p222
};
// k-major row_s channel bases per round/sub (add u): l0 0..57; l1 region base 60
// stride 100; l2 region base 360 stride 96.  (validated round 3)
static __device__ const short L2CBN[9][3] = {
  {0,0,0},{60,0,0},{360,0,0},{32,0,0},{92,108,124},{392,408,0},{48,0,0},{140,150,0},{424,434,444}
};

// MAC reading f/pw/G from this wave's LDS partition (validated)
template<int NI,int NK>
__device__ inline void mac_seg(const float* __restrict__ fS, const float* __restrict__ gS,
                               const float* __restrict__ pS, unsigned d, float* a){
  float p = pS[d & 255];
  int fb = (d>>8)&255, gb = (int)(d>>16);
  float f[5];
  if constexpr (NI==1){ f[0]=fS[fb]*p; }
  else if constexpr (NI==3){
    float4 t=*(const float4*)(fS+fb); f[0]=t.x*p; f[1]=t.y*p; f[2]=t.z*p;
  } else {
    float4 t=*(const float4*)(fS+fb); f[0]=t.x*p;f[1]=t.y*p;f[2]=t.z*p;f[3]=t.w*p; f[4]=fS[fb+4]*p;
  }
  if constexpr (NK==1){
    if constexpr (NI==1){ a[0] += f[0]*gS[gb]; }
    else {
      float4 g=*(const float4*)(gS+gb);
      float s = f[0]*g.x + f[1]*g.y + f[2]*g.z;
      if constexpr (NI==5) s += f[3]*g.w + f[4]*gS[gb+4];
      a[0] += s;
    }
  } else {
    constexpr int ST = (NK==3)?4:8;
    #pragma unroll
    for (int i=0;i<NI;i++){
      float4 g=*(const float4*)(gS+gb+i*ST);
      a[0]+=f[i]*g.x; a[1]+=f[i]*g.y; a[2]+=f[i]*g.z;
      if constexpr (NK==5){ a[3]+=f[i]*g.w; a[4]+=f[i]*gS[gb+i*ST+4]; }
    }
  }
}

__device__ inline void mac_seg_l3(const float* __restrict__ fS, const float* __restrict__ gS,
                                  const float* __restrict__ pS, unsigned d, float* a){
  float p = pS[d & 255];
  int fb = (d>>8)&255, gb = (int)(d>>16);
  float4 g=*(const float4*)(gS+gb); float g4=gS[gb+4];
  float s = fS[fb]*g.x + fS[fb+1]*g.y + fS[fb+2]*g.z + fS[fb+3]*g.w + fS[fb+4]*g4;
  a[0] += p*s;
}

template<int LAYER>
__global__ __launch_bounds__(256,4) void conv_kernel(
    const int* __restrict__ offs, const int* __restrict__ nodeperm,
    const int* __restrict__ src_perm, const float* __restrict__ vec_perm,
    const float* __restrict__ cgbuf, const float* __restrict__ pw,
    const float* __restrict__ fin,
    const float* __restrict__ linA, const float* __restrict__ linB, const float* __restrict__ linC,
    const float* __restrict__ scA, const float* __restrict__ scB, const float* __restrict__ scC,
    const float* __restrict__ gw,
    float* __restrict__ outp)
{
  constexpr int WST   = (LAYER==1) ? 24  : (LAYER==2) ? 252 : 60;
  constexpr int PWL4  = WST/4;
  constexpr int FIN   = (LAYER==1) ? 8   : 130;
  constexpr int GTOTP = (LAYER==1) ? 16  : (LAYER==2) ? 272 : 24;
  constexpr int GR    = (LAYER==2) ? 5 : 1;
  constexpr int NP    = (LAYER==2) ? 15 : 3;
  constexpr int NACC  = (LAYER==1) ? 5 : (LAYER==2) ? 27 : 1;
  // per-wave LDS partition layout (loop phase / epilogue phase overlaid)
  constexpr int PWPAD = (LAYER==1) ? 32 : (LAYER==2) ? 256 : 64;
  constexpr int FPAD  = (LAYER==1) ? 16 : 180;
  constexpr int GOFF  = PWPAD + FPAD;
  constexpr int ROWSZ = (LAYER==1) ? 72 : (LAYER==2) ? 840 : 58;
  constexpr int LOOPSZ= GOFF + GTOTP;
  constexpr int EPISZ = (LAYER==3) ? 58 : ROWSZ + 64;
  constexpr int RMAX  = (LOOPSZ > EPISZ) ? LOOPSZ : EPISZ;
  constexpr int R     = ((RMAX + 15)/16)*16;

  __shared__ __align__(16) float smem[4*R];

  const int lane = threadIdx.x & 63;
  const int wav  = threadIdx.x >> 6;
  const int n    = nodeperm[blockIdx.x*4 + wav];

  float* __restrict__ pw_s = smem + wav*R;
  float* __restrict__ f_s  = pw_s + PWPAD;
  float* __restrict__ G_s  = pw_s + GOFF;
  float* __restrict__ row_s= pw_s;             // epilogue overlay
  float* __restrict__ s0_s = pw_s + ROWSZ;
  float* __restrict__ g_s  = pw_s + ROWSZ + 32;

  // ---- per-lane constant descriptors ----
  int rm[3] = {-1,-1,-1};
  if constexpr (LAYER != 1){
    #pragma unroll
    for (int r=0;r<3;r++){
      int i = lane + 64*r;
      if (i < 32) rm[r] = i;
      else if (i < 80)  rm[r] = 32 + ((i-32)/3)*4 + (i-32)%3;
      else if (i < 130) rm[r] = 96 + ((i-80)/5)*8 + (i-80)%5;
    }
  }

  unsigned md[9]; int cbs[9]; int l1nk = 0;
  #pragma unroll
  for (int r=0;r<9;r++){ md[r]=0; cbs[r]=0; }
  if constexpr (LAYER==2){
    #pragma unroll
    for (int r=0;r<9;r++){
      #pragma unroll
      for (int s=0;s<3;s++){
        int lo = L2RS[r][s][0], hi = L2RS[r][s][1];
        if (hi > lo && lane >= lo && lane < hi){
          int u = lane - lo;
          int fc = L2RS[r][s][3];
          int flds = (fc==0) ? u : (fc==1) ? 32+4*u : 96+8*u;
          md[r] = (unsigned)(L2RS[r][s][2]+u) | ((unsigned)flds<<8) | ((unsigned)L2RS[r][s][4]<<16);
          cbs[r] = L2CBN[r][s] + u;
        }
      }
    }
  } else if constexpr (LAYER==1){
    if (lane < 24){
      int grp = lane >> 3, u = lane & 7;
      int gb = (grp==0) ? 0 : (grp==1) ? 4 : 8;
      md[0] = (unsigned)(grp*8+u) | ((unsigned)u<<8) | ((unsigned)gb<<16);
      cbs[0] = (grp==0) ? u : (grp==1) ? 8+u : 32+u;
      l1nk = (grp==0) ? 1 : (grp==1) ? 3 : 5;
    }
  } else {
    if (lane < 58){
      int grp = (lane<32) ? 0 : (lane<48) ? 1 : 2;
      int u = lane - ((grp==0)?0:(grp==1)?32:48);
      int flds = (grp==0) ? u : (grp==1) ? 32+4*u : 96+8*u;
      int gb = (grp==0) ? 0 : (grp==1) ? 8 : 16;
      md[0] = (unsigned)(((grp==0)?0:(grp==1)?32:48)+u) | ((unsigned)flds<<8) | ((unsigned)gb<<16);
      cbs[0] = (grp==0) ? u : (grp==1) ? 32+u : 48+u;
    }
  }

  // G-stage per-lane CG coefficients in registers
  float cgr[GR][5];
  bool gc0[GR], gc1[GR];
  #pragma unroll
  for (int rg=0;rg<GR;rg++){
    #pragma unroll
    for (int j=0;j<5;j++) cgr[rg][j] = 0.f;
    gc0[rg] = true; gc1[rg] = false;
    int g = lane + 64*rg;
    if (g < GTOTP){
      for (int p=0;p<NP;p++){
        const short* P = (LAYER==1) ? GP1[p] : (LAYER==2) ? GP2[p] : GP3[p];
        int base = P[0], alloc = P[1];
        if (g >= base && g < base+alloc){
          int S = P[2], ni = P[3], nk = P[4], nj = P[5], yb = P[6], cgo = P[7];
          int i, k; bool valid;
          if (S == 1){ i = g - base; k = 0; valid = (i < ni); }
          else { i = (g-base)/S; k = (g-base)%S; valid = (k < nk); }
          gc0[rg] = (yb == 0); gc1[rg] = (yb == 1);
          if (valid){
            #pragma unroll
            for (int j=0;j<5;j++)
              if (j < nj) cgr[rg][j] = cgbuf[cgo + (i*nj+j)*nk + k];
          } else {
            gc0[rg] = true;
          }
        }
      }
    }
  }

  float acc[NACC];
  #pragma unroll
  for (int i=0;i<NACC;i++) acc[i] = 0.f;

  int beg = offs[n], end = offs[n+1];

  for (int idx=beg; idx<end; ++idx){
    int src = src_perm[idx];
    float vx = vec_perm[3*idx], vy = vec_perm[3*idx+1], vz = vec_perm[3*idx+2];

    float4 pwv = {0,0,0,0};
    if (lane < PWL4) pwv = *(const float4*)&pw[(size_t)idx*WST + lane*4];
    float fv[3] = {0,0,0};
    if constexpr (LAYER==1){
      if (lane < 8) fv[0] = fin[(size_t)src*8 + lane];
    } else {
      #pragma unroll
      for (int r=0;r<3;r++){
        int i = lane + 64*r;
        if (i < 130) fv[r] = fin[(size_t)src*130 + i];
      }
    }

    // Y in registers (all lanes)
    float rinv = rsqrtf(vx*vx + vy*vy + vz*vz);
    float X = vx*rinv, Yv = vy*rinv, Z = vz*rinv;
    const float c3 = 1.7320508075688772f, c15 = 3.872983346207417f;
    float y1 = c3*Yv, y2 = c3*Z, y3 = c3*X;
    float y4 = c15*X*Yv, y5 = c15*Yv*Z, y6 = 1.118033988749895f*(3.f*Z*Z-1.f);
    float y7 = c15*X*Z, y8 = 0.5f*c15*(X*X - Yv*Yv);

    WAVE_SYNC();   // WAR: previous iteration's LDS reads retired

    if (lane < PWL4) *(float4*)&pw_s[lane*4] = pwv;
    if constexpr (LAYER==1){
      if (lane < 8) f_s[lane] = fv[0];
    } else {
      #pragma unroll
      for (int r=0;r<3;r++) if (rm[r] >= 0) f_s[rm[r]] = fv[r];
    }

    #pragma unroll
    for (int rg=0;rg<GR;rg++){
      int g = lane + 64*rg;
      if (g < GTOTP){
        float ya  = gc1[rg] ? y1 : y4;
        float yb2 = gc1[rg] ? y2 : y5;
        float yc  = gc1[rg] ? y3 : y6;
        float t = cgr[rg][0]*ya + cgr[rg][1]*yb2 + cgr[rg][2]*yc + cgr[rg][3]*y7 + cgr[rg][4]*y8;
        G_s[g] = gc0[rg] ? cgr[rg][0] : t;
      }
    }

    WAVE_SYNC();   // RAW: staged data visible

    if constexpr (LAYER==2){
      if (lane<32){
        mac_seg<1,1>(f_s,G_s,pw_s,md[0],&acc[0]);
        mac_seg<1,3>(f_s,G_s,pw_s,md[1],&acc[1]);
        mac_seg<1,5>(f_s,G_s,pw_s,md[2],&acc[4]);
      }
      if (lane<16) mac_seg<3,1>(f_s,G_s,pw_s,md[3],&acc[9]);
      if (lane<48) mac_seg<3,3>(f_s,G_s,pw_s,md[4],&acc[10]);
      if (lane<32) mac_seg<3,5>(f_s,G_s,pw_s,md[5],&acc[13]);
      if (lane<10) mac_seg<5,1>(f_s,G_s,pw_s,md[6],&acc[18]);
      if (lane<20) mac_seg<5,3>(f_s,G_s,pw_s,md[7],&acc[19]);
      if (lane<30) mac_seg<5,5>(f_s,G_s,pw_s,md[8],&acc[22]);
    } else if constexpr (LAYER==1){
      if (lane<24) mac_seg<1,5>(f_s,G_s,pw_s,md[0],&acc[0]);
    } else {
      if (lane<58) mac_seg_l3(f_s,G_s,pw_s,md[0],&acc[0]);
    }
  }

  // ---- epilogue ----
  WAVE_SYNC();
  constexpr float inv = 0.25f;
  if constexpr (LAYER==2){
    constexpr int RNKc[9] = {1,3,5,1,3,5,1,3,5};
    constexpr int AB[9]   = {0,1,4,9,10,13,18,19,22};
    constexpr int CNTc[9] = {32,32,32,16,48,32,10,20,30};
    constexpr int KSc[9]  = {0,100,96,0,100,96,0,100,96};
    #pragma unroll
    for (int r=0;r<9;r++){
      if (lane < CNTc[r]){
        #pragma unroll
        for (int k=0;k<RNKc[r];k++) row_s[cbs[r]+k*KSc[r]] = acc[AB[r]+k]*inv;
      }
    }
  } else if constexpr (LAYER==1){
    if (lane < 24){
      #pragma unroll
      for (int k=0;k<5;k++) if (k < l1nk) row_s[cbs[0]+k*8] = acc[k]*inv;
    }
  } else {
    if (lane < 58) row_s[cbs[0]] = acc[0]*inv;
  }
  WAVE_SYNC();

  const float* fo = fin + (size_t)n*FIN;   // own features (global)

  if constexpr (LAYER==3){
    float v = 0.f;
    if (lane < 58) v += row_s[lane]*linA[lane];
    if (lane < 32) v += fo[lane]*scA[lane];
    #pragma unroll
    for (int d=32; d>0; d>>=1) v += __shfl_down(v, d, 64);
    if (lane==0) outp[n] = v;
  } else {
    constexpr int NU0  = (LAYER==1) ? 8 : 58;
    constexpr int NSC0 = (LAYER==1) ? 8 : 32;
    if (lane < 32){
      float s = 0.f;
      for (int u=0;u<NU0;u++)  s += row_s[u]*linA[u*32+lane];
      for (int u=0;u<NSC0;u++) s += fo[u]*scA[u*32+lane];
      s0_s[lane] = s;
    }
    WAVE_SYNC();
    if (lane < 26){
      float s = 0.f;
      for (int v2=0;v2<32;v2++) s += s0_s[v2]*gw[v2*26+lane];
      g_s[lane] = 1.f/(1.f + __expf(-s));
    }
    WAVE_SYNC();
    for (int c=lane;c<130;c+=64){
      float val;
      if (c < 32){
        float s = s0_s[c];
        val = s/(1.f + __expf(-s));
      } else if (c < 80){
        int u = (c-32)/3, k = (c-32)%3;
        float s = 0.f;
        if constexpr (LAYER==1){
          const float4* rp = (const float4*)&row_s[8+k*8];
          float4 r0 = rp[0], r1 = rp[1];
          s = r0.x*linB[0*16+u]+r0.y*linB[1*16+u]+r0.z*linB[2*16+u]+r0.w*linB[3*16+u]
            + r1.x*linB[4*16+u]+r1.y*linB[5*16+u]+r1.z*linB[6*16+u]+r1.w*linB[7*16+u];
        } else {
          const float4* rp = (const float4*)&row_s[60+k*100];
          #pragma unroll 5
          for (int q=0;q<25;q++){
            float4 rv = rp[q];
            s += rv.x*linB[(4*q+0)*16+u] + rv.y*linB[(4*q+1)*16+u]
               + rv.z*linB[(4*q+2)*16+u] + rv.w*linB[(4*q+3)*16+u];
          }
          for (int up=0;up<16;up++) s += fo[32+up*3+k]*scB[up*16+u];
        }
        val = s*g_s[u];
      } else {
        int u = (c-80)/5, k = (c-80)%5;
        float s = 0.f;
        if constexpr (LAYER==1){
          const float4* rp = (const float4*)&row_s[32+k*8];
          float4 r0 = rp[0], r1 = rp[1];
          s = r0.x*linC[0*10+u]+r0.y*linC[1*10+u]+r0.z*linC[2*10+u]+r0.w*linC[3*10+u]
            + r1.x*linC[4*10+u]+r1.y*linC[5*10+u]+r1.z*linC[6*10+u]+r1.w*linC[7*10+u];
        } else {
          const float4* rp = (const float4*)&row_s[360+k*96];
          #pragma unroll 5
          for (int q=0;q<23;q++){
            float4 rv = rp[q];
            s += rv.x*linC[(4*q+0)*10+u] + rv.y*linC[(4*q+1)*10+u]
               + rv.z*linC[(4*q+2)*10+u] + rv.w*linC[(4*q+3)*10+u];
          }
          s += row_s[360+k*96+92]*linC[92*10+u] + row_s[360+k*96+93]*linC[93*10+u];
          for (int up=0;up<10;up++) s += fo[80+up*5+k]*scC[up*10+u];
        }
        val = s*g_s[16+u];
      }
      outp[(size_t)n*130 + c] = val;
    }
  }
}

// ===========================================================================
extern "C" void kernel_launch(void* const* d_in, const int* in_sizes, int n_in,
                              void* d_out, int out_size, void* d_ws, size_t ws_size,
                              hipStream_t stream){
  (void)in_sizes; (void)n_in; (void)out_size; (void)ws_size;
  const float* x        = (const float*)d_in[0];
  const float* edge_vec = (const float*)d_in[1];
  const float* fc1_w1   = (const float*)d_in[2];
  const float* fc1_w2   = (const float*)d_in[3];
  const float* lin1_l0  = (const float*)d_in[4];
  const float* lin1_l1  = (const float*)d_in[5];
  const float* lin1_l2  = (const float*)d_in[6];
  const float* sc1_l0   = (const float*)d_in[7];
  const float* gate1_w  = (const float*)d_in[8];
  const float* fc2_w1   = (const float*)d_in[9];
  const float* fc2_w2   = (const float*)d_in[10];
  const float* lin2_l0  = (const float*)d_in[11];
  const float* lin2_l1  = (const float*)d_in[12];
  const float* lin2_l2  = (const float*)d_in[13];
  const float* sc2_l0   = (const float*)d_in[14];
  const float* sc2_l1   = (const float*)d_in[15];
  const float* sc2_l2   = (const float*)d_in[16];
  const float* gate2_w  = (const float*)d_in[17];
  const float* fc3_w1   = (const float*)d_in[18];
  const float* fc3_w2   = (const float*)d_in[19];
  const float* lin3_l0  = (const float*)d_in[20];
  const float* sc3_l0   = (const float*)d_in[21];
  const int* edge_src   = (const int*)d_in[22];
  const int* edge_dst   = (const int*)d_in[23];
  float* out = (float*)d_out;

  char* base = (char*)d_ws;
  size_t off = 0;
  auto carve = [&](size_t bytes)->char*{
    char* p = base + off;
    off = (off + bytes + 255) & ~(size_t)255;
    return p;
  };
  int*   deg      = (int*)  carve((size_t)N_NODES*4);
  int*   offs     = (int*)  carve((size_t)(N_NODES+1)*4);
  int*   cursor   = (int*)  carve((size_t)N_NODES*4);
  int*   eids     = (int*)  carve((size_t)N_EDGES*4);
  int*   pos      = (int*)  carve((size_t)N_EDGES*4);
  int*   src_perm = (int*)  carve((size_t)N_EDGES*4);
  float* vec_perm = (float*)carve((size_t)N_EDGES*12);
  float* cgbuf    = (float*)carve(615*4);
  int*   dhist    = (int*)  carve(64*4);
  int*   dcur     = (int*)  carve(64*4);
  int*   nodeperm = (int*)  carve((size_t)N_NODES*4);
  float* hfeats   = (float*)carve((size_t)N_NODES*130*4);
  float* h2feats  = (float*)carve((size_t)N_NODES*130*4);
  float* pwbuf    = (float*)carve((size_t)N_EDGES*252*4);

  hipMemsetAsync(deg, 0, (size_t)N_NODES*4, stream);
  hipMemsetAsync(dhist, 0, 64*4, stream);
  hist_kernel<<<N_EDGES/256, 256, 0, stream>>>(edge_dst, deg);
  scan_kernel<<<1, 1024, 0, stream>>>(deg, offs, cursor);
  scatter_kernel<<<N_EDGES/256, 256, 0, stream>>>(edge_dst, cursor, eids, pos);
  perm_kernel<<<N_EDGES/256, 256, 0, stream>>>(eids, edge_src, edge_vec, src_perm, vec_perm);
  dhist_kernel<<<(N_NODES+255)/256, 256, 0, stream>>>(deg, dhist);
  dscan_kernel<<<1, 64, 0, stream>>>(dhist, dcur);
  dscatter_kernel<<<(N_NODES+255)/256, 256, 0, stream>>>(deg, dcur, nodeperm);
  cg_init_kernel<<<15, 128, 0, stream>>>(cgbuf);

  mlp_kernel<24,24><<<N_EDGES/64, 256, 0, stream>>>(edge_vec, fc1_w1, fc1_w2, pos, pwbuf);
  conv_kernel<1><<<(N_NODES+3)/4, 256, 0, stream>>>(offs, nodeperm, src_perm, vec_perm, cgbuf, pwbuf,
      x, lin1_l0, lin1_l1, lin1_l2, sc1_l0, nullptr, nullptr, gate1_w, hfeats);
  mlp_kernel<252,252><<<N_EDGES/64, 256, 0, stream>>>(edge_vec, fc2_w1, fc2_w2, pos, pwbuf);
  conv_kernel<2><<<(N_NODES+3)/4, 256, 0, stream>>>(offs, nodeperm, src_perm, vec_perm, cgbuf, pwbuf,
      hfeats, lin2_l0, lin2_l1, lin2_l2, sc2_l0, sc2_l1, sc2_l2, gate2_w, h2feats);
  mlp_kernel<58,60><<<N_EDGES/64, 256, 0, stream>>>(edge_vec, fc3_w1, fc3_w2, pos, pwbuf);
  conv_kernel<3><<<(N_NODES+3)/4, 256, 0, stream>>>(offs, nodeperm, src_perm, vec_perm, cgbuf, pwbuf,
      h2feats, lin3_l0, nullptr, nullptr, sc3_l0, nullptr, nullptr, nullptr, out);
}

// Round 9
// 602.088 us; speedup vs baseline: 1.0840x; 1.0840x over previous
//
#include <hip/hip_runtime.h>
#include <hip/hip_bf16.h>

#define N_NODES 10000
#define N_EDGES 160000

// ===========================================================================
// CG tensor computation (device-side, validated round 1)
// ===========================================================================
static __device__ const int CG_COMBOS[15][4] = {
  {0,0,0,0},{0,1,1,1},{0,2,2,10},{1,0,1,35},{1,1,0,44},{1,1,1,53},{1,1,2,80},
  {1,2,1,125},{1,2,2,170},{2,0,2,245},{2,1,1,270},{2,1,2,315},{2,2,0,390},
  {2,2,1,415},{2,2,2,490}
};

__device__ inline double factd(int n){ double f=1.0; for(int i=2;i<=n;i++) f*=(double)i; return f; }

__device__ double cg_complex_dev(int j1,int m1,int j2,int m2,int j3,int m3){
  if (m1+m2 != m3) return 0.0;
  double pref = sqrt((2.0*j3+1.0)*factd(j1+j2-j3)*factd(j1-j2+j3)*factd(-j1+j2+j3)/factd(j1+j2+j3+1));
  pref *= sqrt(factd(j1+m1)*factd(j1-m1)*factd(j2+m2)*factd(j2-m2)*factd(j3+m3)*factd(j3-m3));
  int kmin = 0; if (j2-j3-m1 > kmin) kmin = j2-j3-m1; if (j1-j3+m2 > kmin) kmin = j1-j3+m2;
  int kmax = j1+j2-j3; if (j1-m1 < kmax) kmax = j1-m1; if (j2+m2 < kmax) kmax = j2+m2;
  double s = 0.0;
  for (int k=kmin; k<=kmax; ++k){
    double d = factd(k)*factd(j1+j2-j3-k)*factd(j1-m1-k)*factd(j2+m2-k)*factd(j3-j2+m1+k)*factd(j3-j1-m2+k);
    s += ((k&1) ? -1.0 : 1.0)/d;
  }
  return pref*s;
}

__device__ inline void q_elem(int l, int r, int c, double* re, double* im){
  const double s2 = 0.7071067811865476;
  *re = 0.0; *im = 0.0;
  int mr = r - l, mc = c - l;
  if (mr == 0){ if (mc == 0) *re = 1.0; return; }
  if (mr > 0){
    int m = mr;
    if (mc == m)       *re = (m&1) ? -s2 : s2;
    else if (mc == -m) *re = s2;
  } else {
    int m = -mr;
    if (mc == -m)      *im = s2;
    else if (mc == m)  *im = (m&1) ? s2 : -s2;
  }
}

__global__ __launch_bounds__(128) void cg_init_kernel(float* __restrict__ cgbuf){
  __shared__ double Cr[125], Ci[125];
  __shared__ double Qr[3][25], Qi[3][25];
  __shared__ double Kr[125], Ki[125];
  __shared__ double red[128];
  int t = threadIdx.x, b = blockIdx.x;
  int l1 = CG_COMBOS[b][0], l2 = CG_COMBOS[b][1], l3 = CG_COMBOS[b][2], off = CG_COMBOS[b][3];
  int n1 = 2*l1+1, n2 = 2*l2+1, n3 = 2*l3+1;
  int tot = n1*n2*n3;
  for (int i=t; i<tot; i+=128){ Cr[i]=0.0; Ci[i]=0.0; }
  __syncthreads();
  if (t < n1*n2){
    int m1 = t/n2 - l1, m2 = t%n2 - l2, m3 = m1+m2;
    if (m3 >= -l3 && m3 <= l3)
      Cr[t*n3 + (l3+m3)] = cg_complex_dev(l1,m1,l2,m2,l3,m3);
  }
  int ls[3] = {l1,l2,l3};
  for (int q=0;q<3;q++){
    int n = 2*ls[q]+1;
    if (t < n*n) q_elem(ls[q], t/n, t%n, &Qr[q][t], &Qi[q][t]);
  }
  __syncthreads();
  if (t < tot){
    int i = t/(n2*n3), j = (t/n3)%n2, k = t%n3;
    double sr=0.0, si=0.0;
    for (int a=0;a<n1;a++){
      double q1r = Qr[0][i*n1+a], q1i = -Qi[0][i*n1+a];
      for (int bb=0;bb<n2;bb++){
        double q2r = Qr[1][j*n2+bb], q2i = -Qi[1][j*n2+bb];
        double pr = q1r*q2r - q1i*q2i, pi = q1r*q2i + q1i*q2r;
        for (int c=0;c<n3;c++){
          double cr = Cr[(a*n2+bb)*n3+c], ci = Ci[(a*n2+bb)*n3+c];
          if (cr==0.0 && ci==0.0) continue;
          double q3r = Qr[2][k*n3+c], q3i = Qi[2][k*n3+c];
          double tr = pr*q3r - pi*q3i, ti = pr*q3i + pi*q3r;
          sr += tr*cr - ti*ci;
          si += tr*ci + ti*cr;
        }
      }
    }
    Kr[t]=sr; Ki[t]=si;
  }
  __syncthreads();
  double v = (t<tot) ? fabs(Kr[t]) : 0.0;
  red[t]=v; __syncthreads();
  for (int s=64;s>0;s>>=1){ if (t<s && red[t+s]>red[t]) red[t]=red[t+s]; __syncthreads(); }
  double maxRe = red[0]; __syncthreads();
  v = (t<tot) ? fabs(Ki[t]) : 0.0;
  red[t]=v; __syncthreads();
  for (int s=64;s>0;s>>=1){ if (t<s && red[t+s]>red[t]) red[t]=red[t+s]; __syncthreads(); }
  double maxIm = red[0]; __syncthreads();
  bool useIm = (maxIm > maxRe);
  double pick = (t<tot) ? (useIm ? -Ki[t] : Kr[t]) : 0.0;
  red[t] = pick*pick; __syncthreads();
  for (int s=64;s>0;s>>=1){ if (t<s) red[t]+=red[t+s]; __syncthreads(); }
  double scale = sqrt((double)n3) / sqrt(red[0]);
  if (t<tot) cgbuf[off+t] = (float)(pick*scale);
}

// ===========================================================================
// CSR build + degree-descending node permutation (load balance)
// ===========================================================================
__global__ void hist_kernel(const int* __restrict__ dst, int* __restrict__ deg){
  int e = blockIdx.x*256 + threadIdx.x;
  atomicAdd(&deg[dst[e]], 1);
}

__global__ __launch_bounds__(1024) void scan_kernel(const int* __restrict__ deg,
                                                    int* __restrict__ offs,
                                                    int* __restrict__ cursor){
  __shared__ int lds[1024];
  __shared__ int run_s;
  int tid = threadIdx.x;
  if (tid==0) run_s = 0;
  __syncthreads();
  for (int base=0; base<N_NODES; base+=1024){
    int i = base + tid;
    int vv = (i<N_NODES) ? deg[i] : 0;
    lds[tid]=vv; __syncthreads();
    for (int off=1; off<1024; off<<=1){
      int a = lds[tid];
      int b = (tid>=off) ? lds[tid-off] : 0;
      __syncthreads();
      lds[tid] = a + b;
      __syncthreads();
    }
    int incl = lds[tid];
    int run = run_s;
    if (i < N_NODES){ int ex = run + incl - vv; offs[i]=ex; cursor[i]=ex; }
    __syncthreads();
    if (tid==1023) run_s = run + lds[1023];
    __syncthreads();
  }
  if (tid==0) offs[N_NODES] = run_s;
}

__global__ void scatter_kernel(const int* __restrict__ dst, int* __restrict__ cursor,
                               int* __restrict__ eids, int* __restrict__ pos){
  int e = blockIdx.x*256 + threadIdx.x;
  int p = atomicAdd(&cursor[dst[e]], 1);
  eids[p] = e;
  pos[e] = p;
}

__global__ void perm_kernel(const int* __restrict__ eids, const int* __restrict__ edge_src,
                            const float* __restrict__ edge_vec,
                            int* __restrict__ src_perm, float* __restrict__ vec_perm){
  int p = blockIdx.x*256 + threadIdx.x;
  int e = eids[p];
  src_perm[p] = edge_src[e];
  vec_perm[3*p]   = edge_vec[3*e];
  vec_perm[3*p+1] = edge_vec[3*e+1];
  vec_perm[3*p+2] = edge_vec[3*e+2];
}

// Degree-descending counting sort of nodes — single workgroup, LDS bins.
// (replaces the round-8 global-atomic version whose hot-bin serialization
//  cost ~50 µs: 64 bins, ~1000 nodes in the mode bin → serialized L2 RMWs)
__global__ __launch_bounds__(1024) void nodesort_kernel(const int* __restrict__ deg,
                                                        int* __restrict__ nodeperm){
  __shared__ int bins[64];
  __shared__ int cur[64];
  int tid = threadIdx.x;
  if (tid < 64) bins[tid] = 0;
  __syncthreads();
  for (int i = tid; i < N_NODES; i += 1024){
    int d = deg[i]; if (d > 63) d = 63;
    atomicAdd(&bins[63-d], 1);            // LDS atomic: ~cycles, not ~100 cyc
  }
  __syncthreads();
  if (tid == 0){
    int run = 0;
    for (int b=0;b<64;b++){ cur[b] = run; run += bins[b]; }
  }
  __syncthreads();
  for (int i = tid; i < N_NODES; i += 1024){
    int d = deg[i]; if (d > 63) d = 63;
    int p = atomicAdd(&cur[63-d], 1);
    nodeperm[p] = i;
  }
}

// ===========================================================================
// Per-edge radial MLP (unchanged, writes pw in CSR order)
// ===========================================================================
template<int WOUT, int WST>
__global__ __launch_bounds__(256) void mlp_kernel(const float* __restrict__ edge_vec,
    const float* __restrict__ w1, const float* __restrict__ w2,
    const int* __restrict__ pos, float* __restrict__ pw){
  __shared__ __align__(16) float emb_s[64*10];
  __shared__ __align__(16) float hid_s[100*64];
  __shared__ int pos_s[64];
  int t = threadIdx.x;
  int eb = blockIdx.x*64;
  if (t < 64){
    int e = eb + t;
    pos_s[t] = pos[e];
    float vx = edge_vec[3*e], vy = edge_vec[3*e+1], vz = edge_vec[3*e+2];
    float r = sqrtf(vx*vx + vy*vy + vz*vz);
    const float EMBC = 1.14136f * 7.3890560989306495f * 3.1622776601683795f;
    #pragma unroll
    for (int bb=0; bb<10; bb++){
      float c = 5.0f*(float)(bb+1)/11.0f;
      float d = (r - c) * (11.0f/5.0f);
      float t1 = d + 1.0f, t2 = 1.0f - d;
      float u1 = (t1 > 0.0f) ? __expf(-1.0f/t1) : 0.0f;
      float u2 = (t2 > 0.0f) ? __expf(-1.0f/t2) : 0.0f;
      emb_s[t*10+bb] = EMBC*u1*u2;
    }
  }
  __syncthreads();
  {
    int e = t & 63, h0 = t >> 6;
    int col = ((e&3)<<4) | (e>>2);
    #pragma unroll
    for (int k=0;k<25;k++){
      int h = h0 + 4*k;
      float s = 0.f;
      #pragma unroll
      for (int bb=0;bb<10;bb++) s += emb_s[e*10+bb]*w1[bb*100+h];
      hid_s[h*64+col] = s/(1.0f+__expf(-s));
    }
  }
  __syncthreads();
  constexpr int NQ = (WOUT+63)/64;
  int cq = t & 63, eg = t >> 6;
  float acc[NQ][16];
  #pragma unroll
  for (int q=0;q<NQ;q++)
    #pragma unroll
    for (int m=0;m<16;m++) acc[q][m]=0.f;
  for (int h=0; h<100; h++){
    float wv[NQ];
    #pragma unroll
    for (int q=0;q<NQ;q++){ int c = cq + 64*q; wv[q] = (c<WOUT) ? w2[h*WOUT+c] : 0.f; }
    const float4* hp = (const float4*)&hid_s[h*64 + (eg<<4)];
    float4 ha = hp[0], hb = hp[1], hc = hp[2], hd = hp[3];
    float hv[16] = {ha.x,ha.y,ha.z,ha.w, hb.x,hb.y,hb.z,hb.w,
                    hc.x,hc.y,hc.z,hc.w, hd.x,hd.y,hd.z,hd.w};
    #pragma unroll
    for (int m=0;m<16;m++){
      #pragma unroll
      for (int q=0;q<NQ;q++) acc[q][m] += wv[q]*hv[m];
    }
  }
  #pragma unroll
  for (int m=0;m<16;m++){
    int row = pos_s[eg + 4*m];
    #pragma unroll
    for (int q=0;q<NQ;q++){
      int c = cq + 64*q;
      if (c < WOUT) pw[(size_t)row*WST + c] = acc[q][m];
    }
  }
}

// ===========================================================================
// Conv: 4 nodes per 256-thread block (degree-matched via nodeperm), one wave
// per node, private LDS/wave. Wave-synchronous. (round-5 structure)
// ===========================================================================
#define WAVE_SYNC() asm volatile("s_waitcnt lgkmcnt(0)" ::: "memory")

// Padded G-layout path tables: {base, alloc, S, ni, nk, nj, yb, cgoff}
static __device__ const short GP1[3][8] = {
  {0,4,1,1,1,1,0,0},{4,4,4,1,3,3,1,1},{8,8,8,1,5,5,4,10}
};
static __device__ const short GP3[3][8] = {
  {0,8,1,1,1,1,0,0},{8,8,1,3,1,3,1,44},{16,8,1,5,1,5,4,390}
};
static __device__ const short GP2[15][8] = {
  {0,4,1,1,1,1,0,0},     // p000
  {4,4,4,1,3,3,1,1},     // p011
  {8,8,8,1,5,5,4,10},    // p022
  {16,12,4,3,3,1,0,35},  // p101
  {28,4,1,3,1,3,1,44},   // p110
  {32,12,4,3,3,3,1,53},  // p111
  {44,24,8,3,5,3,1,80},  // p112
  {68,12,4,3,3,5,4,125}, // p121
  {80,24,8,3,5,5,4,170}, // p122
  {104,40,8,5,5,1,0,245},// p202
  {144,20,4,5,3,3,1,270},// p211
  {164,40,8,5,5,3,1,315},// p212
  {204,8,1,5,1,5,4,390}, // p220
  {212,20,4,5,3,5,4,415},// p221
  {232,40,8,5,5,5,4,490} // p222
};

// Layer-2 msg-round subseg table: [round][sub] = {lo, hi, woff, fcls, gbase}
static __device__ const short L2RS[9][3][5] = {
  {{0,32,  0,0,  0},{0,0,0,0,0},{0,0,0,0,0}},   // r0 <1,1> p000
  {{0,32, 32,0,  4},{0,0,0,0,0},{0,0,0,0,0}},   // r1 <1,3> p011
  {{0,32, 64,0,  8},{0,0,0,0,0},{0,0,0,0,0}},   // r2 <1,5> p022
  {{0,16,112,1, 28},{0,0,0,0,0},{0,0,0,0,0}},   // r3 <3,1> p110
  {{0,16, 96,1, 16},{16,32,128,1,32},{32,48,160,1,68}},  // r4 <3,3> p101,p111,p121
  {{0,16,144,1, 44},{16,32,176,1,80},{0,0,0,0,0}},       // r5 <3,5> p112,p122
  {{0,10,222,2,204},{0,0,0,0,0},{0,0,0,0,0}},   // r6 <5,1> p220
  {{0,10,202,2,144},{10,20,232,2,212},{0,0,0,0,0}},      // r7 <5,3> p211,p221
  {{0,10,192,2,104},{10,20,212,2,164},{20,30,242,2,232}} // r8 <5,5> p202,p212,p222
};
// k-major row_s channel bases per round/sub (add u): l0 0..57; l1 region base 60
// stride 100; l2 region base 360 stride 96.  (validated round 3)
static __device__ const short L2CBN[9][3] = {
  {0,0,0},{60,0,0},{360,0,0},{32,0,0},{92,108,124},{392,408,0},{48,0,0},{140,150,0},{424,434,444}
};

// MAC reading f/pw/G from this wave's LDS partition (validated)
template<int NI,int NK>
__device__ inline void mac_seg(const float* __restrict__ fS, const float* __restrict__ gS,
                               const float* __restrict__ pS, unsigned d, float* a){
  float p = pS[d & 255];
  int fb = (d>>8)&255, gb = (int)(d>>16);
  float f[5];
  if constexpr (NI==1){ f[0]=fS[fb]*p; }
  else if constexpr (NI==3){
    float4 t=*(const float4*)(fS+fb); f[0]=t.x*p; f[1]=t.y*p; f[2]=t.z*p;
  } else {
    float4 t=*(const float4*)(fS+fb); f[0]=t.x*p;f[1]=t.y*p;f[2]=t.z*p;f[3]=t.w*p; f[4]=fS[fb+4]*p;
  }
  if constexpr (NK==1){
    if constexpr (NI==1){ a[0] += f[0]*gS[gb]; }
    else {
      float4 g=*(const float4*)(gS+gb);
      float s = f[0]*g.x + f[1]*g.y + f[2]*g.z;
      if constexpr (NI==5) s += f[3]*g.w + f[4]*gS[gb+4];
      a[0] += s;
    }
  } else {
    constexpr int ST = (NK==3)?4:8;
    #pragma unroll
    for (int i=0;i<NI;i++){
      float4 g=*(const float4*)(gS+gb+i*ST);
      a[0]+=f[i]*g.x; a[1]+=f[i]*g.y; a[2]+=f[i]*g.z;
      if constexpr (NK==5){ a[3]+=f[i]*g.w; a[4]+=f[i]*gS[gb+i*ST+4]; }
    }
  }
}

__device__ inline void mac_seg_l3(const float* __restrict__ fS, const float* __restrict__ gS,
                                  const float* __restrict__ pS, unsigned d, float* a){
  float p = pS[d & 255];
  int fb = (d>>8)&255, gb = (int)(d>>16);
  float4 g=*(const float4*)(gS+gb); float g4=gS[gb+4];
  float s = fS[fb]*g.x + fS[fb+1]*g.y + fS[fb+2]*g.z + fS[fb+3]*g.w + fS[fb+4]*g4;
  a[0] += p*s;
}

template<int LAYER>
__global__ __launch_bounds__(256,4) void conv_kernel(
    const int* __restrict__ offs, const int* __restrict__ nodeperm,
    const int* __restrict__ src_perm, const float* __restrict__ vec_perm,
    const float* __restrict__ cgbuf, const float* __restrict__ pw,
    const float* __restrict__ fin,
    const float* __restrict__ linA, const float* __restrict__ linB, const float* __restrict__ linC,
    const float* __restrict__ scA, const float* __restrict__ scB, const float* __restrict__ scC,
    const float* __restrict__ gw,
    float* __restrict__ outp)
{
  constexpr int WST   = (LAYER==1) ? 24  : (LAYER==2) ? 252 : 60;
  constexpr int PWL4  = WST/4;
  constexpr int FIN   = (LAYER==1) ? 8   : 130;
  constexpr int GTOTP = (LAYER==1) ? 16  : (LAYER==2) ? 272 : 24;
  constexpr int GR    = (LAYER==2) ? 5 : 1;
  constexpr int NP    = (LAYER==2) ? 15 : 3;
  constexpr int NACC  = (LAYER==1) ? 5 : (LAYER==2) ? 27 : 1;
  // per-wave LDS partition layout (loop phase / epilogue phase overlaid)
  constexpr int PWPAD = (LAYER==1) ? 32 : (LAYER==2) ? 256 : 64;
  constexpr int FPAD  = (LAYER==1) ? 16 : 180;
  constexpr int GOFF  = PWPAD + FPAD;
  constexpr int ROWSZ = (LAYER==1) ? 72 : (LAYER==2) ? 840 : 58;
  constexpr int LOOPSZ= GOFF + GTOTP;
  constexpr int EPISZ = (LAYER==3) ? 58 : ROWSZ + 64;
  constexpr int RMAX  = (LOOPSZ > EPISZ) ? LOOPSZ : EPISZ;
  constexpr int R     = ((RMAX + 15)/16)*16;

  __shared__ __align__(16) float smem[4*R];

  const int lane = threadIdx.x & 63;
  const int wav  = threadIdx.x >> 6;
  const int n    = nodeperm[blockIdx.x*4 + wav];

  float* __restrict__ pw_s = smem + wav*R;
  float* __restrict__ f_s  = pw_s + PWPAD;
  float* __restrict__ G_s  = pw_s + GOFF;
  float* __restrict__ row_s= pw_s;             // epilogue overlay
  float* __restrict__ s0_s = pw_s + ROWSZ;
  float* __restrict__ g_s  = pw_s + ROWSZ + 32;

  // ---- per-lane constant descriptors ----
  int rm[3] = {-1,-1,-1};
  if constexpr (LAYER != 1){
    #pragma unroll
    for (int r=0;r<3;r++){
      int i = lane + 64*r;
      if (i < 32) rm[r] = i;
      else if (i < 80)  rm[r] = 32 + ((i-32)/3)*4 + (i-32)%3;
      else if (i < 130) rm[r] = 96 + ((i-80)/5)*8 + (i-80)%5;
    }
  }

  unsigned md[9]; int cbs[9]; int l1nk = 0;
  #pragma unroll
  for (int r=0;r<9;r++){ md[r]=0; cbs[r]=0; }
  if constexpr (LAYER==2){
    #pragma unroll
    for (int r=0;r<9;r++){
      #pragma unroll
      for (int s=0;s<3;s++){
        int lo = L2RS[r][s][0], hi = L2RS[r][s][1];
        if (hi > lo && lane >= lo && lane < hi){
          int u = lane - lo;
          int fc = L2RS[r][s][3];
          int flds = (fc==0) ? u : (fc==1) ? 32+4*u : 96+8*u;
          md[r] = (unsigned)(L2RS[r][s][2]+u) | ((unsigned)flds<<8) | ((unsigned)L2RS[r][s][4]<<16);
          cbs[r] = L2CBN[r][s] + u;
        }
      }
    }
  } else if constexpr (LAYER==1){
    if (lane < 24){
      int grp = lane >> 3, u = lane & 7;
      int gb = (grp==0) ? 0 : (grp==1) ? 4 : 8;
      md[0] = (unsigned)(grp*8+u) | ((unsigned)u<<8) | ((unsigned)gb<<16);
      cbs[0] = (grp==0) ? u : (grp==1) ? 8+u : 32+u;
      l1nk = (grp==0) ? 1 : (grp==1) ? 3 : 5;
    }
  } else {
    if (lane < 58){
      int grp = (lane<32) ? 0 : (lane<48) ? 1 : 2;
      int u = lane - ((grp==0)?0:(grp==1)?32:48);
      int flds = (grp==0) ? u : (grp==1) ? 32+4*u : 96+8*u;
      int gb = (grp==0) ? 0 : (grp==1) ? 8 : 16;
      md[0] = (unsigned)(((grp==0)?0:(grp==1)?32:48)+u) | ((unsigned)flds<<8) | ((unsigned)gb<<16);
      cbs[0] = (grp==0) ? u : (grp==1) ? 32+u : 48+u;
    }
  }

  // G-stage per-lane CG coefficients in registers
  float cgr[GR][5];
  bool gc0[GR], gc1[GR];
  #pragma unroll
  for (int rg=0;rg<GR;rg++){
    #pragma unroll
    for (int j=0;j<5;j++) cgr[rg][j] = 0.f;
    gc0[rg] = true; gc1[rg] = false;
    int g = lane + 64*rg;
    if (g < GTOTP){
      for (int p=0;p<NP;p++){
        const short* P = (LAYER==1) ? GP1[p] : (LAYER==2) ? GP2[p] : GP3[p];
        int base = P[0], alloc = P[1];
        if (g >= base && g < base+alloc){
          int S = P[2], ni = P[3], nk = P[4], nj = P[5], yb = P[6], cgo = P[7];
          int i, k; bool valid;
          if (S == 1){ i = g - base; k = 0; valid = (i < ni); }
          else { i = (g-base)/S; k = (g-base)%S; valid = (k < nk); }
          gc0[rg] = (yb == 0); gc1[rg] = (yb == 1);
          if (valid){
            #pragma unroll
            for (int j=0;j<5;j++)
              if (j < nj) cgr[rg][j] = cgbuf[cgo + (i*nj+j)*nk + k];
          } else {
            gc0[rg] = true;
          }
        }
      }
    }
  }

  float acc[NACC];
  #pragma unroll
  for (int i=0;i<NACC;i++) acc[i] = 0.f;

  int beg = offs[n], end = offs[n+1];

  for (int idx=beg; idx<end; ++idx){
    int src = src_perm[idx];
    float vx = vec_perm[3*idx], vy = vec_perm[3*idx+1], vz = vec_perm[3*idx+2];

    float4 pwv = {0,0,0,0};
    if (lane < PWL4) pwv = *(const float4*)&pw[(size_t)idx*WST + lane*4];
    float fv[3] = {0,0,0};
    if constexpr (LAYER==1){
      if (lane < 8) fv[0] = fin[(size_t)src*8 + lane];
    } else {
      #pragma unroll
      for (int r=0;r<3;r++){
        int i = lane + 64*r;
        if (i < 130) fv[r] = fin[(size_t)src*130 + i];
      }
    }

    // Y in registers (all lanes)
    float rinv = rsqrtf(vx*vx + vy*vy + vz*vz);
    float X = vx*rinv, Yv = vy*rinv, Z = vz*rinv;
    const float c3 = 1.7320508075688772f, c15 = 3.872983346207417f;
    float y1 = c3*Yv, y2 = c3*Z, y3 = c3*X;
    float y4 = c15*X*Yv, y5 = c15*Yv*Z, y6 = 1.118033988749895f*(3.f*Z*Z-1.f);
    float y7 = c15*X*Z, y8 = 0.5f*c15*(X*X - Yv*Yv);

    WAVE_SYNC();   // WAR: previous iteration's LDS reads retired

    if (lane < PWL4) *(float4*)&pw_s[lane*4] = pwv;
    if constexpr (LAYER==1){
      if (lane < 8) f_s[lane] = fv[0];
    } else {
      #pragma unroll
      for (int r=0;r<3;r++) if (rm[r] >= 0) f_s[rm[r]] = fv[r];
    }

    #pragma unroll
    for (int rg=0;rg<GR;rg++){
      int g = lane + 64*rg;
      if (g < GTOTP){
        float ya  = gc1[rg] ? y1 : y4;
        float yb2 = gc1[rg] ? y2 : y5;
        float yc  = gc1[rg] ? y3 : y6;
        float t = cgr[rg][0]*ya + cgr[rg][1]*yb2 + cgr[rg][2]*yc + cgr[rg][3]*y7 + cgr[rg][4]*y8;
        G_s[g] = gc0[rg] ? cgr[rg][0] : t;
      }
    }

    WAVE_SYNC();   // RAW: staged data visible

    if constexpr (LAYER==2){
      if (lane<32){
        mac_seg<1,1>(f_s,G_s,pw_s,md[0],&acc[0]);
        mac_seg<1,3>(f_s,G_s,pw_s,md[1],&acc[1]);
        mac_seg<1,5>(f_s,G_s,pw_s,md[2],&acc[4]);
      }
      if (lane<16) mac_seg<3,1>(f_s,G_s,pw_s,md[3],&acc[9]);
      if (lane<48) mac_seg<3,3>(f_s,G_s,pw_s,md[4],&acc[10]);
      if (lane<32) mac_seg<3,5>(f_s,G_s,pw_s,md[5],&acc[13]);
      if (lane<10) mac_seg<5,1>(f_s,G_s,pw_s,md[6],&acc[18]);
      if (lane<20) mac_seg<5,3>(f_s,G_s,pw_s,md[7],&acc[19]);
      if (lane<30) mac_seg<5,5>(f_s,G_s,pw_s,md[8],&acc[22]);
    } else if constexpr (LAYER==1){
      if (lane<24) mac_seg<1,5>(f_s,G_s,pw_s,md[0],&acc[0]);
    } else {
      if (lane<58) mac_seg_l3(f_s,G_s,pw_s,md[0],&acc[0]);
    }
  }

  // ---- epilogue ----
  WAVE_SYNC();
  constexpr float inv = 0.25f;
  if constexpr (LAYER==2){
    constexpr int RNKc[9] = {1,3,5,1,3,5,1,3,5};
    constexpr int AB[9]   = {0,1,4,9,10,13,18,19,22};
    constexpr int CNTc[9] = {32,32,32,16,48,32,10,20,30};
    constexpr int KSc[9]  = {0,100,96,0,100,96,0,100,96};
    #pragma unroll
    for (int r=0;r<9;r++){
      if (lane < CNTc[r]){
        #pragma unroll
        for (int k=0;k<RNKc[r];k++) row_s[cbs[r]+k*KSc[r]] = acc[AB[r]+k]*inv;
      }
    }
  } else if constexpr (LAYER==1){
    if (lane < 24){
      #pragma unroll
      for (int k=0;k<5;k++) if (k < l1nk) row_s[cbs[0]+k*8] = acc[k]*inv;
    }
  } else {
    if (lane < 58) row_s[cbs[0]] = acc[0]*inv;
  }
  WAVE_SYNC();

  const float* fo = fin + (size_t)n*FIN;   // own features (global)

  if constexpr (LAYER==3){
    float v = 0.f;
    if (lane < 58) v += row_s[lane]*linA[lane];
    if (lane < 32) v += fo[lane]*scA[lane];
    #pragma unroll
    for (int d=32; d>0; d>>=1) v += __shfl_down(v, d, 64);
    if (lane==0) outp[n] = v;
  } else {
    constexpr int NU0  = (LAYER==1) ? 8 : 58;
    constexpr int NSC0 = (LAYER==1) ? 8 : 32;
    if (lane < 32){
      float s = 0.f;
      for (int u=0;u<NU0;u++)  s += row_s[u]*linA[u*32+lane];
      for (int u=0;u<NSC0;u++) s += fo[u]*scA[u*32+lane];
      s0_s[lane] = s;
    }
    WAVE_SYNC();
    if (lane < 26){
      float s = 0.f;
      for (int v2=0;v2<32;v2++) s += s0_s[v2]*gw[v2*26+lane];
      g_s[lane] = 1.f/(1.f + __expf(-s));
    }
    WAVE_SYNC();
    for (int c=lane;c<130;c+=64){
      float val;
      if (c < 32){
        float s = s0_s[c];
        val = s/(1.f + __expf(-s));
      } else if (c < 80){
        int u = (c-32)/3, k = (c-32)%3;
        float s = 0.f;
        if constexpr (LAYER==1){
          const float4* rp = (const float4*)&row_s[8+k*8];
          float4 r0 = rp[0], r1 = rp[1];
          s = r0.x*linB[0*16+u]+r0.y*linB[1*16+u]+r0.z*linB[2*16+u]+r0.w*linB[3*16+u]
            + r1.x*linB[4*16+u]+r1.y*linB[5*16+u]+r1.z*linB[6*16+u]+r1.w*linB[7*16+u];
        } else {
          const float4* rp = (const float4*)&row_s[60+k*100];
          #pragma unroll 5
          for (int q=0;q<25;q++){
            float4 rv = rp[q];
            s += rv.x*linB[(4*q+0)*16+u] + rv.y*linB[(4*q+1)*16+u]
               + rv.z*linB[(4*q+2)*16+u] + rv.w*linB[(4*q+3)*16+u];
          }
          for (int up=0;up<16;up++) s += fo[32+up*3+k]*scB[up*16+u];
        }
        val = s*g_s[u];
      } else {
        int u = (c-80)/5, k = (c-80)%5;
        float s = 0.f;
        if constexpr (LAYER==1){
          const float4* rp = (const float4*)&row_s[32+k*8];
          float4 r0 = rp[0], r1 = rp[1];
          s = r0.x*linC[0*10+u]+r0.y*linC[1*10+u]+r0.z*linC[2*10+u]+r0.w*linC[3*10+u]
            + r1.x*linC[4*10+u]+r1.y*linC[5*10+u]+r1.z*linC[6*10+u]+r1.w*linC[7*10+u];
        } else {
          const float4* rp = (const float4*)&row_s[360+k*96];
          #pragma unroll 5
          for (int q=0;q<23;q++){
            float4 rv = rp[q];
            s += rv.x*linC[(4*q+0)*10+u] + rv.y*linC[(4*q+1)*10+u]
               + rv.z*linC[(4*q+2)*10+u] + rv.w*linC[(4*q+3)*10+u];
          }
          s += row_s[360+k*96+92]*linC[92*10+u] + row_s[360+k*96+93]*linC[93*10+u];
          for (int up=0;up<10;up++) s += fo[80+up*5+k]*scC[up*10+u];
        }
        val = s*g_s[16+u];
      }
      outp[(size_t)n*130 + c] = val;
    }
  }
}

// ===========================================================================
extern "C" void kernel_launch(void* const* d_in, const int* in_sizes, int n_in,
                              void* d_out, int out_size, void* d_ws, size_t ws_size,
                              hipStream_t stream){
  (void)in_sizes; (void)n_in; (void)out_size; (void)ws_size;
  const float* x        = (const float*)d_in[0];
  const float* edge_vec = (const float*)d_in[1];
  const float* fc1_w1   = (const float*)d_in[2];
  const float* fc1_w2   = (const float*)d_in[3];
  const float* lin1_l0  = (const float*)d_in[4];
  const float* lin1_l1  = (const float*)d_in[5];
  const float* lin1_l2  = (const float*)d_in[6];
  const float* sc1_l0   = (const float*)d_in[7];
  const float* gate1_w  = (const float*)d_in[8];
  const float* fc2_w1   = (const float*)d_in[9];
  const float* fc2_w2   = (const float*)d_in[10];
  const float* lin2_l0  = (const float*)d_in[11];
  const float* lin2_l1  = (const float*)d_in[12];
  const float* lin2_l2  = (const float*)d_in[13];
  const float* sc2_l0   = (const float*)d_in[14];
  const float* sc2_l1   = (const float*)d_in[15];
  const float* sc2_l2   = (const float*)d_in[16];
  const float* gate2_w  = (const float*)d_in[17];
  const float* fc3_w1   = (const float*)d_in[18];
  const float* fc3_w2   = (const float*)d_in[19];
  const float* lin3_l0  = (const float*)d_in[20];
  const float* sc3_l0   = (const float*)d_in[21];
  const int* edge_src   = (const int*)d_in[22];
  const int* edge_dst   = (const int*)d_in[23];
  float* out = (float*)d_out;

  char* base = (char*)d_ws;
  size_t off = 0;
  auto carve = [&](size_t bytes)->char*{
    char* p = base + off;
    off = (off + bytes + 255) & ~(size_t)255;
    return p;
  };
  int*   deg      = (int*)  carve((size_t)N_NODES*4);
  int*   offs     = (int*)  carve((size_t)(N_NODES+1)*4);
  int*   cursor   = (int*)  carve((size_t)N_NODES*4);
  int*   eids     = (int*)  carve((size_t)N_EDGES*4);
  int*   pos      = (int*)  carve((size_t)N_EDGES*4);
  int*   src_perm = (int*)  carve((size_t)N_EDGES*4);
  float* vec_perm = (float*)carve((size_t)N_EDGES*12);
  float* cgbuf    = (float*)carve(615*4);
  int*   nodeperm = (int*)  carve((size_t)N_NODES*4);
  float* hfeats   = (float*)carve((size_t)N_NODES*130*4);
  float* h2feats  = (float*)carve((size_t)N_NODES*130*4);
  float* pwbuf    = (float*)carve((size_t)N_EDGES*252*4);

  hipMemsetAsync(deg, 0, (size_t)N_NODES*4, stream);
  hist_kernel<<<N_EDGES/256, 256, 0, stream>>>(edge_dst, deg);
  scan_kernel<<<1, 1024, 0, stream>>>(deg, offs, cursor);
  scatter_kernel<<<N_EDGES/256, 256, 0, stream>>>(edge_dst, cursor, eids, pos);
  perm_kernel<<<N_EDGES/256, 256, 0, stream>>>(eids, edge_src, edge_vec, src_perm, vec_perm);
  nodesort_kernel<<<1, 1024, 0, stream>>>(deg, nodeperm);
  cg_init_kernel<<<15, 128, 0, stream>>>(cgbuf);

  mlp_kernel<24,24><<<N_EDGES/64, 256, 0, stream>>>(edge_vec, fc1_w1, fc1_w2, pos, pwbuf);
  conv_kernel<1><<<(N_NODES+3)/4, 256, 0, stream>>>(offs, nodeperm, src_perm, vec_perm, cgbuf, pwbuf,
      x, lin1_l0, lin1_l1, lin1_l2, sc1_l0, nullptr, nullptr, gate1_w, hfeats);
  mlp_kernel<252,252><<<N_EDGES/64, 256, 0, stream>>>(edge_vec, fc2_w1, fc2_w2, pos, pwbuf);
  conv_kernel<2><<<(N_NODES+3)/4, 256, 0, stream>>>(offs, nodeperm, src_perm, vec_perm, cgbuf, pwbuf,
      hfeats, lin2_l0, lin2_l1, lin2_l2, sc2_l0, sc2_l1, sc2_l2, gate2_w, h2feats);
  mlp_kernel<58,60><<<N_EDGES/64, 256, 0, stream>>>(edge_vec, fc3_w1, fc3_w2, pos, pwbuf);
  conv_kernel<3><<<(N_NODES+3)/4, 256, 0, stream>>>(offs, nodeperm, src_perm, vec_perm, cgbuf, pwbuf,
      h2feats, lin3_l0, nullptr, nullptr, sc3_l0, nullptr, nullptr, nullptr, out);
}

// Round 10
// 579.996 us; speedup vs baseline: 1.1253x; 1.0381x over previous
//
#include <hip/hip_runtime.h>
#include <hip/hip_bf16.h>

#define N_NODES 10000
#define N_EDGES 160000

// ===========================================================================
// CG tensor computation (device-side, validated round 1)
// ===========================================================================
static __device__ const int CG_COMBOS[15][4] = {
  {0,0,0,0},{0,1,1,1},{0,2,2,10},{1,0,1,35},{1,1,0,44},{1,1,1,53},{1,1,2,80},
  {1,2,1,125},{1,2,2,170},{2,0,2,245},{2,1,1,270},{2,1,2,315},{2,2,0,390},
  {2,2,1,415},{2,2,2,490}
};

__device__ inline double factd(int n){ double f=1.0; for(int i=2;i<=n;i++) f*=(double)i; return f; }

__device__ double cg_complex_dev(int j1,int m1,int j2,int m2,int j3,int m3){
  if (m1+m2 != m3) return 0.0;
  double pref = sqrt((2.0*j3+1.0)*factd(j1+j2-j3)*factd(j1-j2+j3)*factd(-j1+j2+j3)/factd(j1+j2+j3+1));
  pref *= sqrt(factd(j1+m1)*factd(j1-m1)*factd(j2+m2)*factd(j2-m2)*factd(j3+m3)*factd(j3-m3));
  int kmin = 0; if (j2-j3-m1 > kmin) kmin = j2-j3-m1; if (j1-j3+m2 > kmin) kmin = j1-j3+m2;
  int kmax = j1+j2-j3; if (j1-m1 < kmax) kmax = j1-m1; if (j2+m2 < kmax) kmax = j2+m2;
  double s = 0.0;
  for (int k=kmin; k<=kmax; ++k){
    double d = factd(k)*factd(j1+j2-j3-k)*factd(j1-m1-k)*factd(j2+m2-k)*factd(j3-j2+m1+k)*factd(j3-j1-m2+k);
    s += ((k&1) ? -1.0 : 1.0)/d;
  }
  return pref*s;
}

__device__ inline void q_elem(int l, int r, int c, double* re, double* im){
  const double s2 = 0.7071067811865476;
  *re = 0.0; *im = 0.0;
  int mr = r - l, mc = c - l;
  if (mr == 0){ if (mc == 0) *re = 1.0; return; }
  if (mr > 0){
    int m = mr;
    if (mc == m)       *re = (m&1) ? -s2 : s2;
    else if (mc == -m) *re = s2;
  } else {
    int m = -mr;
    if (mc == -m)      *im = s2;
    else if (mc == m)  *im = (m&1) ? s2 : -s2;
  }
}

__global__ __launch_bounds__(128) void cg_init_kernel(float* __restrict__ cgbuf){
  __shared__ double Cr[125], Ci[125];
  __shared__ double Qr[3][25], Qi[3][25];
  __shared__ double Kr[125], Ki[125];
  __shared__ double red[128];
  int t = threadIdx.x, b = blockIdx.x;
  int l1 = CG_COMBOS[b][0], l2 = CG_COMBOS[b][1], l3 = CG_COMBOS[b][2], off = CG_COMBOS[b][3];
  int n1 = 2*l1+1, n2 = 2*l2+1, n3 = 2*l3+1;
  int tot = n1*n2*n3;
  for (int i=t; i<tot; i+=128){ Cr[i]=0.0; Ci[i]=0.0; }
  __syncthreads();
  if (t < n1*n2){
    int m1 = t/n2 - l1, m2 = t%n2 - l2, m3 = m1+m2;
    if (m3 >= -l3 && m3 <= l3)
      Cr[t*n3 + (l3+m3)] = cg_complex_dev(l1,m1,l2,m2,l3,m3);
  }
  int ls[3] = {l1,l2,l3};
  for (int q=0;q<3;q++){
    int n = 2*ls[q]+1;
    if (t < n*n) q_elem(ls[q], t/n, t%n, &Qr[q][t], &Qi[q][t]);
  }
  __syncthreads();
  if (t < tot){
    int i = t/(n2*n3), j = (t/n3)%n2, k = t%n3;
    double sr=0.0, si=0.0;
    for (int a=0;a<n1;a++){
      double q1r = Qr[0][i*n1+a], q1i = -Qi[0][i*n1+a];
      for (int bb=0;bb<n2;bb++){
        double q2r = Qr[1][j*n2+bb], q2i = -Qi[1][j*n2+bb];
        double pr = q1r*q2r - q1i*q2i, pi = q1r*q2i + q1i*q2r;
        for (int c=0;c<n3;c++){
          double cr = Cr[(a*n2+bb)*n3+c], ci = Ci[(a*n2+bb)*n3+c];
          if (cr==0.0 && ci==0.0) continue;
          double q3r = Qr[2][k*n3+c], q3i = Qi[2][k*n3+c];
          double tr = pr*q3r - pi*q3i, ti = pr*q3i + pi*q3r;
          sr += tr*cr - ti*ci;
          si += tr*ci + ti*cr;
        }
      }
    }
    Kr[t]=sr; Ki[t]=si;
  }
  __syncthreads();
  double v = (t<tot) ? fabs(Kr[t]) : 0.0;
  red[t]=v; __syncthreads();
  for (int s=64;s>0;s>>=1){ if (t<s && red[t+s]>red[t]) red[t]=red[t+s]; __syncthreads(); }
  double maxRe = red[0]; __syncthreads();
  v = (t<tot) ? fabs(Ki[t]) : 0.0;
  red[t]=v; __syncthreads();
  for (int s=64;s>0;s>>=1){ if (t<s && red[t+s]>red[t]) red[t]=red[t+s]; __syncthreads(); }
  double maxIm = red[0]; __syncthreads();
  bool useIm = (maxIm > maxRe);
  double pick = (t<tot) ? (useIm ? -Ki[t] : Kr[t]) : 0.0;
  red[t] = pick*pick; __syncthreads();
  for (int s=64;s>0;s>>=1){ if (t<s) red[t]+=red[t+s]; __syncthreads(); }
  double scale = sqrt((double)n3) / sqrt(red[0]);
  if (t<tot) cgbuf[off+t] = (float)(pick*scale);
}

// ===========================================================================
// CSR build + degree-descending node permutation (load balance)
// ===========================================================================
__global__ void hist_kernel(const int* __restrict__ dst, int* __restrict__ deg){
  int e = blockIdx.x*256 + threadIdx.x;
  atomicAdd(&deg[dst[e]], 1);
}

__global__ __launch_bounds__(1024) void scan_kernel(const int* __restrict__ deg,
                                                    int* __restrict__ offs,
                                                    int* __restrict__ cursor){
  __shared__ int lds[1024];
  __shared__ int run_s;
  int tid = threadIdx.x;
  if (tid==0) run_s = 0;
  __syncthreads();
  for (int base=0; base<N_NODES; base+=1024){
    int i = base + tid;
    int vv = (i<N_NODES) ? deg[i] : 0;
    lds[tid]=vv; __syncthreads();
    for (int off=1; off<1024; off<<=1){
      int a = lds[tid];
      int b = (tid>=off) ? lds[tid-off] : 0;
      __syncthreads();
      lds[tid] = a + b;
      __syncthreads();
    }
    int incl = lds[tid];
    int run = run_s;
    if (i < N_NODES){ int ex = run + incl - vv; offs[i]=ex; cursor[i]=ex; }
    __syncthreads();
    if (tid==1023) run_s = run + lds[1023];
    __syncthreads();
  }
  if (tid==0) offs[N_NODES] = run_s;
}

__global__ void scatter_kernel(const int* __restrict__ dst, int* __restrict__ cursor,
                               int* __restrict__ eids, int* __restrict__ pos){
  int e = blockIdx.x*256 + threadIdx.x;
  int p = atomicAdd(&cursor[dst[e]], 1);
  eids[p] = e;
  pos[e] = p;
}

__global__ void perm_kernel(const int* __restrict__ eids, const int* __restrict__ edge_src,
                            const float* __restrict__ edge_vec,
                            int* __restrict__ src_perm, float* __restrict__ vec_perm){
  int p = blockIdx.x*256 + threadIdx.x;
  int e = eids[p];
  src_perm[p] = edge_src[e];
  vec_perm[3*p]   = edge_vec[3*e];
  vec_perm[3*p+1] = edge_vec[3*e+1];
  vec_perm[3*p+2] = edge_vec[3*e+2];
}

// Degree-descending counting sort of nodes — single workgroup, LDS bins.
__global__ __launch_bounds__(1024) void nodesort_kernel(const int* __restrict__ deg,
                                                        int* __restrict__ nodeperm){
  __shared__ int bins[64];
  __shared__ int cur[64];
  int tid = threadIdx.x;
  if (tid < 64) bins[tid] = 0;
  __syncthreads();
  for (int i = tid; i < N_NODES; i += 1024){
    int d = deg[i]; if (d > 63) d = 63;
    atomicAdd(&bins[63-d], 1);
  }
  __syncthreads();
  if (tid == 0){
    int run = 0;
    for (int b=0;b<64;b++){ cur[b] = run; run += bins[b]; }
  }
  __syncthreads();
  for (int i = tid; i < N_NODES; i += 1024){
    int d = deg[i]; if (d > 63) d = 63;
    int p = atomicAdd(&cur[63-d], 1);
    nodeperm[p] = i;
  }
}

// ===========================================================================
// Per-edge radial MLP (unchanged, writes pw in CSR order)
// ===========================================================================
template<int WOUT, int WST>
__global__ __launch_bounds__(256) void mlp_kernel(const float* __restrict__ edge_vec,
    const float* __restrict__ w1, const float* __restrict__ w2,
    const int* __restrict__ pos, float* __restrict__ pw){
  __shared__ __align__(16) float emb_s[64*10];
  __shared__ __align__(16) float hid_s[100*64];
  __shared__ int pos_s[64];
  int t = threadIdx.x;
  int eb = blockIdx.x*64;
  if (t < 64){
    int e = eb + t;
    pos_s[t] = pos[e];
    float vx = edge_vec[3*e], vy = edge_vec[3*e+1], vz = edge_vec[3*e+2];
    float r = sqrtf(vx*vx + vy*vy + vz*vz);
    const float EMBC = 1.14136f * 7.3890560989306495f * 3.1622776601683795f;
    #pragma unroll
    for (int bb=0; bb<10; bb++){
      float c = 5.0f*(float)(bb+1)/11.0f;
      float d = (r - c) * (11.0f/5.0f);
      float t1 = d + 1.0f, t2 = 1.0f - d;
      float u1 = (t1 > 0.0f) ? __expf(-1.0f/t1) : 0.0f;
      float u2 = (t2 > 0.0f) ? __expf(-1.0f/t2) : 0.0f;
      emb_s[t*10+bb] = EMBC*u1*u2;
    }
  }
  __syncthreads();
  {
    int e = t & 63, h0 = t >> 6;
    int col = ((e&3)<<4) | (e>>2);
    #pragma unroll
    for (int k=0;k<25;k++){
      int h = h0 + 4*k;
      float s = 0.f;
      #pragma unroll
      for (int bb=0;bb<10;bb++) s += emb_s[e*10+bb]*w1[bb*100+h];
      hid_s[h*64+col] = s/(1.0f+__expf(-s));
    }
  }
  __syncthreads();
  constexpr int NQ = (WOUT+63)/64;
  int cq = t & 63, eg = t >> 6;
  float acc[NQ][16];
  #pragma unroll
  for (int q=0;q<NQ;q++)
    #pragma unroll
    for (int m=0;m<16;m++) acc[q][m]=0.f;
  for (int h=0; h<100; h++){
    float wv[NQ];
    #pragma unroll
    for (int q=0;q<NQ;q++){ int c = cq + 64*q; wv[q] = (c<WOUT) ? w2[h*WOUT+c] : 0.f; }
    const float4* hp = (const float4*)&hid_s[h*64 + (eg<<4)];
    float4 ha = hp[0], hb = hp[1], hc = hp[2], hd = hp[3];
    float hv[16] = {ha.x,ha.y,ha.z,ha.w, hb.x,hb.y,hb.z,hb.w,
                    hc.x,hc.y,hc.z,hc.w, hd.x,hd.y,hd.z,hd.w};
    #pragma unroll
    for (int m=0;m<16;m++){
      #pragma unroll
      for (int q=0;q<NQ;q++) acc[q][m] += wv[q]*hv[m];
    }
  }
  #pragma unroll
  for (int m=0;m<16;m++){
    int row = pos_s[eg + 4*m];
    #pragma unroll
    for (int q=0;q<NQ;q++){
      int c = cq + 64*q;
      if (c < WOUT) pw[(size_t)row*WST + c] = acc[q][m];
    }
  }
}

// ===========================================================================
// Conv: 4 nodes per 256-thread block (degree-matched via nodeperm), one wave
// per node, private LDS/wave. Wave-synchronous. Layers 1/3 batch multiple
// edges per iteration (EPI=4/2) to amortize syncs and gather latency.
// ===========================================================================
#define WAVE_SYNC() asm volatile("s_waitcnt lgkmcnt(0)" ::: "memory")

// Padded G-layout path tables: {base, alloc, S, ni, nk, nj, yb, cgoff}
static __device__ const short GP1[3][8] = {
  {0,4,1,1,1,1,0,0},{4,4,4,1,3,3,1,1},{8,8,8,1,5,5,4,10}
};
static __device__ const short GP3[3][8] = {
  {0,8,1,1,1,1,0,0},{8,8,1,3,1,3,1,44},{16,8,1,5,1,5,4,390}
};
static __device__ const short GP2[15][8] = {
  {0,4,1,1,1,1,0,0},     // p000
  {4,4,4,1,3,3,1,1},     // p011
  {8,8,8,1,5,5,4,10},    // p022
  {16,12,4,3,3,1,0,35},  // p101
  {28,4,1,3,1,3,1,44},   // p110
  {32,12,4,3,3,3,1,53},  // p111
  {44,24,8,3,5,3,1,80},  // p112
  {68,12,4,3,3,5,4,125}, // p121
  {80,24,8,3,5,5,4,170}, // p122
  {104,40,8,5,5,1,0,245},// p202
  {144,20,4,5,3,3,1,270},// p211
  {164,40,8,5,5,3,1,315},// p212
  {204,8,1,5,1,5,4,390}, // p220
  {212,20,4,5,3,5,4,415},// p221
  {232,40,8,5,5,5,4,490} // p222
};

// Layer-2 msg-round subseg table: [round][sub] = {lo, hi, woff, fcls, gbase}
static __device__ const short L2RS[9][3][5] = {
  {{0,32,  0,0,  0},{0,0,0,0,0},{0,0,0,0,0}},   // r0 <1,1> p000
  {{0,32, 32,0,  4},{0,0,0,0,0},{0,0,0,0,0}},   // r1 <1,3> p011
  {{0,32, 64,0,  8},{0,0,0,0,0},{0,0,0,0,0}},   // r2 <1,5> p022
  {{0,16,112,1, 28},{0,0,0,0,0},{0,0,0,0,0}},   // r3 <3,1> p110
  {{0,16, 96,1, 16},{16,32,128,1,32},{32,48,160,1,68}},  // r4 <3,3> p101,p111,p121
  {{0,16,144,1, 44},{16,32,176,1,80},{0,0,0,0,0}},       // r5 <3,5> p112,p122
  {{0,10,222,2,204},{0,0,0,0,0},{0,0,0,0,0}},   // r6 <5,1> p220
  {{0,10,202,2,144},{10,20,232,2,212},{0,0,0,0,0}},      // r7 <5,3> p211,p221
  {{0,10,192,2,104},{10,20,212,2,164},{20,30,242,2,232}} // r8 <5,5> p202,p212,p222
};
// k-major row_s channel bases per round/sub (add u): l0 0..57; l1 region base 60
// stride 100; l2 region base 360 stride 96.  (validated round 3)
static __device__ const short L2CBN[9][3] = {
  {0,0,0},{60,0,0},{360,0,0},{32,0,0},{92,108,124},{392,408,0},{48,0,0},{140,150,0},{424,434,444}
};

// MAC reading f/pw/G from an LDS partition (validated)
template<int NI,int NK>
__device__ inline void mac_seg(const float* __restrict__ fS, const float* __restrict__ gS,
                               const float* __restrict__ pS, unsigned d, float* a){
  float p = pS[d & 255];
  int fb = (d>>8)&255, gb = (int)(d>>16);
  float f[5];
  if constexpr (NI==1){ f[0]=fS[fb]*p; }
  else if constexpr (NI==3){
    float4 t=*(const float4*)(fS+fb); f[0]=t.x*p; f[1]=t.y*p; f[2]=t.z*p;
  } else {
    float4 t=*(const float4*)(fS+fb); f[0]=t.x*p;f[1]=t.y*p;f[2]=t.z*p;f[3]=t.w*p; f[4]=fS[fb+4]*p;
  }
  if constexpr (NK==1){
    if constexpr (NI==1){ a[0] += f[0]*gS[gb]; }
    else {
      float4 g=*(const float4*)(gS+gb);
      float s = f[0]*g.x + f[1]*g.y + f[2]*g.z;
      if constexpr (NI==5) s += f[3]*g.w + f[4]*gS[gb+4];
      a[0] += s;
    }
  } else {
    constexpr int ST = (NK==3)?4:8;
    #pragma unroll
    for (int i=0;i<NI;i++){
      float4 g=*(const float4*)(gS+gb+i*ST);
      a[0]+=f[i]*g.x; a[1]+=f[i]*g.y; a[2]+=f[i]*g.z;
      if constexpr (NK==5){ a[3]+=f[i]*g.w; a[4]+=f[i]*gS[gb+i*ST+4]; }
    }
  }
}

__device__ inline void mac_seg_l3(const float* __restrict__ fS, const float* __restrict__ gS,
                                  const float* __restrict__ pS, unsigned d, float* a){
  float p = pS[d & 255];
  int fb = (d>>8)&255, gb = (int)(d>>16);
  float4 g=*(const float4*)(gS+gb); float g4=gS[gb+4];
  float s = fS[fb]*g.x + fS[fb+1]*g.y + fS[fb+2]*g.z + fS[fb+3]*g.w + fS[fb+4]*g4;
  a[0] += p*s;
}

#define Y_FROM_VEC() \
    float rinv = rsqrtf(vx*vx + vy*vy + vz*vz); \
    float X = vx*rinv, Yv = vy*rinv, Z = vz*rinv; \
    const float c3 = 1.7320508075688772f, c15 = 3.872983346207417f; \
    float y1 = c3*Yv, y2 = c3*Z, y3 = c3*X; \
    float y4 = c15*X*Yv, y5 = c15*Yv*Z, y6 = 1.118033988749895f*(3.f*Z*Z-1.f); \
    float y7 = c15*X*Z, y8 = 0.5f*c15*(X*X - Yv*Yv);

template<int LAYER>
__global__ __launch_bounds__(256,4) void conv_kernel(
    const int* __restrict__ offs, const int* __restrict__ nodeperm,
    const int* __restrict__ src_perm, const float* __restrict__ vec_perm,
    const float* __restrict__ cgbuf, const float* __restrict__ pw,
    const float* __restrict__ fin,
    const float* __restrict__ linA, const float* __restrict__ linB, const float* __restrict__ linC,
    const float* __restrict__ scA, const float* __restrict__ scB, const float* __restrict__ scC,
    const float* __restrict__ gw,
    float* __restrict__ outp)
{
  constexpr int WST   = (LAYER==1) ? 24  : (LAYER==2) ? 252 : 60;
  constexpr int PWL4  = WST/4;
  constexpr int FIN   = (LAYER==1) ? 8   : 130;
  constexpr int GTOTP = (LAYER==1) ? 16  : (LAYER==2) ? 272 : 24;
  constexpr int GR    = (LAYER==2) ? 5 : 1;
  constexpr int NP    = (LAYER==2) ? 15 : 3;
  constexpr int NACC  = (LAYER==1) ? 5 : (LAYER==2) ? 27 : 1;
  constexpr int EPI   = (LAYER==1) ? 4 : (LAYER==2) ? 1 : 2;
  // per-edge LDS partition layout (loop) / epilogue overlay
  constexpr int PWPAD = (LAYER==1) ? 32 : (LAYER==2) ? 256 : 64;
  constexpr int FPAD  = (LAYER==1) ? 16 : 180;
  constexpr int GOFF  = PWPAD + FPAD;                     // 48 / 436 / 244
  constexpr int HALFA = (LAYER==1) ? 80 : (LAYER==2) ? 708 : 272;  // partition stride
  constexpr int ROWSZ = (LAYER==1) ? 72 : (LAYER==2) ? 840 : 58;
  constexpr int LOOPSZ= EPI*HALFA;                        // 320 / 708 / 544
  constexpr int EPISZ = (LAYER==3) ? 58 : ROWSZ + 64;
  constexpr int RMAX  = (LOOPSZ > EPISZ) ? LOOPSZ : EPISZ;
  constexpr int R     = ((RMAX + 15)/16)*16;              // 320 / 912 / 544

  __shared__ __align__(16) float smem[4*R];

  const int lane = threadIdx.x & 63;
  const int wav  = threadIdx.x >> 6;
  const int n    = nodeperm[blockIdx.x*4 + wav];

  float* __restrict__ pw_s = smem + wav*R;       // partition-0 base
  float* __restrict__ f_s  = pw_s + PWPAD;       // (layer-2 path)
  float* __restrict__ G_s  = pw_s + GOFF;
  float* __restrict__ row_s= pw_s;               // epilogue overlay
  float* __restrict__ s0_s = pw_s + ROWSZ;
  float* __restrict__ g_s  = pw_s + ROWSZ + 32;

  // ---- per-lane constant descriptors ----
  int rm[3] = {-1,-1,-1};
  if constexpr (LAYER != 1){
    #pragma unroll
    for (int r=0;r<3;r++){
      int i = lane + 64*r;
      if (i < 32) rm[r] = i;
      else if (i < 80)  rm[r] = 32 + ((i-32)/3)*4 + (i-32)%3;
      else if (i < 130) rm[r] = 96 + ((i-80)/5)*8 + (i-80)%5;
    }
  }

  unsigned md[9]; int cbs[9]; int l1nk = 0;
  #pragma unroll
  for (int r=0;r<9;r++){ md[r]=0; cbs[r]=0; }
  if constexpr (LAYER==2){
    #pragma unroll
    for (int r=0;r<9;r++){
      #pragma unroll
      for (int s=0;s<3;s++){
        int lo = L2RS[r][s][0], hi = L2RS[r][s][1];
        if (hi > lo && lane >= lo && lane < hi){
          int u = lane - lo;
          int fc = L2RS[r][s][3];
          int flds = (fc==0) ? u : (fc==1) ? 32+4*u : 96+8*u;
          md[r] = (unsigned)(L2RS[r][s][2]+u) | ((unsigned)flds<<8) | ((unsigned)L2RS[r][s][4]<<16);
          cbs[r] = L2CBN[r][s] + u;
        }
      }
    }
  } else if constexpr (LAYER==1){
    if (lane < 24){
      int grp = lane >> 3, u = lane & 7;
      int gb = (grp==0) ? 0 : (grp==1) ? 4 : 8;
      md[0] = (unsigned)(grp*8+u) | ((unsigned)u<<8) | ((unsigned)gb<<16);
      cbs[0] = (grp==0) ? u : (grp==1) ? 8+u : 32+u;
      l1nk = (grp==0) ? 1 : (grp==1) ? 3 : 5;
    }
  } else {
    if (lane < 58){
      int grp = (lane<32) ? 0 : (lane<48) ? 1 : 2;
      int u = lane - ((grp==0)?0:(grp==1)?32:48);
      int flds = (grp==0) ? u : (grp==1) ? 32+4*u : 96+8*u;
      int gb = (grp==0) ? 0 : (grp==1) ? 8 : 16;
      md[0] = (unsigned)(((grp==0)?0:(grp==1)?32:48)+u) | ((unsigned)flds<<8) | ((unsigned)gb<<16);
      cbs[0] = (grp==0) ? u : (grp==1) ? 32+u : 48+u;
    }
  }

  // G-stage per-lane CG coefficients in registers.
  // L1: every lane owns G element (lane&15) of edge (lane>>4) — full round.
  // L3: lanes 0..47 own G element (lane%24) of edge (lane/24).
  float cgr[GR][5];
  bool gc0[GR], gc1[GR];
  #pragma unroll
  for (int rg=0;rg<GR;rg++){
    #pragma unroll
    for (int j=0;j<5;j++) cgr[rg][j] = 0.f;
    gc0[rg] = true; gc1[rg] = false;
    int g; bool gvalid;
    if constexpr (LAYER==1){ g = lane & 15; gvalid = true; }
    else if constexpr (LAYER==3){ g = lane % 24; gvalid = (lane < 48); }
    else { g = lane + 64*rg; gvalid = (g < GTOTP); }
    if (gvalid){
      for (int p=0;p<NP;p++){
        const short* P = (LAYER==1) ? GP1[p] : (LAYER==2) ? GP2[p] : GP3[p];
        int base = P[0], alloc = P[1];
        if (g >= base && g < base+alloc){
          int S = P[2], ni = P[3], nk = P[4], nj = P[5], yb = P[6], cgo = P[7];
          int i, k; bool valid;
          if (S == 1){ i = g - base; k = 0; valid = (i < ni); }
          else { i = (g-base)/S; k = (g-base)%S; valid = (k < nk); }
          gc0[rg] = (yb == 0); gc1[rg] = (yb == 1);
          if (valid){
            #pragma unroll
            for (int j=0;j<5;j++)
              if (j < nj) cgr[rg][j] = cgbuf[cgo + (i*nj+j)*nk + k];
          } else {
            gc0[rg] = true;
          }
        }
      }
    }
  }

  float acc[NACC];
  #pragma unroll
  for (int i=0;i<NACC;i++) acc[i] = 0.f;

  int beg = offs[n], end = offs[n+1];

  if constexpr (LAYER==1){
    // ---- 4 edges per iteration ----
    const int j_pw = lane/6,  c_pw = lane - j_pw*6;   // lanes 0..23
    const int j_f  = lane>>3, f_i  = lane&7;          // lanes 0..31
    const int j_g  = lane>>4;                         // all lanes
    const int g16  = lane & 15;
    for (int base=beg; base<end; base+=4){
      float4 pwv = {0,0,0,0};
      if (lane<24 && base+j_pw<end)
        pwv = *(const float4*)&pw[(size_t)(base+j_pw)*24 + c_pw*4];
      float fvv = 0.f;
      if (lane<32){
        int ef = base+j_f; if (ef>=end) ef = end-1;
        fvv = fin[(size_t)src_perm[ef]*8 + f_i];
      }
      int ee = base+j_g; if (ee>=end) ee = end-1;
      float vx = vec_perm[3*ee], vy = vec_perm[3*ee+1], vz = vec_perm[3*ee+2];
      Y_FROM_VEC();

      WAVE_SYNC();   // WAR: previous iteration's LDS reads retired

      if (lane<24) *(float4*)&pw_s[j_pw*80 + c_pw*4] = pwv;
      if (lane<32) pw_s[j_f*80 + 32 + f_i] = fvv;
      {
        float ya  = gc1[0] ? y1 : y4;
        float yb2 = gc1[0] ? y2 : y5;
        float yc  = gc1[0] ? y3 : y6;
        float t = cgr[0][0]*ya + cgr[0][1]*yb2 + cgr[0][2]*yc + cgr[0][3]*y7 + cgr[0][4]*y8;
        pw_s[j_g*80 + 48 + g16] = gc0[0] ? cgr[0][0] : t;
      }

      WAVE_SYNC();   // RAW: staged data visible

      if (lane<24){
        #pragma unroll
        for (int j=0;j<4;j++)
          mac_seg<1,5>(pw_s + j*80 + 32, pw_s + j*80 + 48, pw_s + j*80, md[0], &acc[0]);
      }
    }
  } else if constexpr (LAYER==3){
    // ---- 2 edges per iteration ----
    const int j_pw = lane/15, c_pw = lane - j_pw*15;  // lanes 0..29
    const int j_g  = (lane<24) ? 0 : 1;               // for lane<48
    for (int base=beg; base<end; base+=2){
      int e1 = (base+1<end) ? base+1 : base;
      float4 pwv = {0,0,0,0};
      if (lane<30 && base+j_pw<end)
        pwv = *(const float4*)&pw[(size_t)(base+j_pw)*60 + c_pw*4];
      int s0 = src_perm[base], s1 = src_perm[e1];
      float fv0[3] = {0,0,0}, fv1[3] = {0,0,0};
      #pragma unroll
      for (int r=0;r<3;r++){
        int i = lane + 64*r;
        if (i < 130){
          fv0[r] = fin[(size_t)s0*130 + i];
          fv1[r] = fin[(size_t)s1*130 + i];
        }
      }
      int ee = (lane<48 && j_g==1) ? e1 : base;
      float vx = vec_perm[3*ee], vy = vec_perm[3*ee+1], vz = vec_perm[3*ee+2];
      Y_FROM_VEC();

      WAVE_SYNC();   // WAR

      if (lane<30) *(float4*)&pw_s[j_pw*272 + c_pw*4] = pwv;
      #pragma unroll
      for (int r=0;r<3;r++) if (rm[r]>=0){
        pw_s[64 + rm[r]]        = fv0[r];
        pw_s[272 + 64 + rm[r]]  = fv1[r];
      }
      if (lane<48){
        float ya  = gc1[0] ? y1 : y4;
        float yb2 = gc1[0] ? y2 : y5;
        float yc  = gc1[0] ? y3 : y6;
        float t = cgr[0][0]*ya + cgr[0][1]*yb2 + cgr[0][2]*yc + cgr[0][3]*y7 + cgr[0][4]*y8;
        pw_s[j_g*272 + 244 + (lane%24)] = gc0[0] ? cgr[0][0] : t;
      }

      WAVE_SYNC();   // RAW

      if (lane<58){
        #pragma unroll
        for (int j=0;j<2;j++)
          mac_seg_l3(pw_s + j*272 + 64, pw_s + j*272 + 244, pw_s + j*272, md[0], &acc[0]);
      }
    }
  } else {
    // ---- layer 2: round-9 loop unchanged ----
    for (int idx=beg; idx<end; ++idx){
      int src = src_perm[idx];
      float vx = vec_perm[3*idx], vy = vec_perm[3*idx+1], vz = vec_perm[3*idx+2];

      float4 pwv = {0,0,0,0};
      if (lane < PWL4) pwv = *(const float4*)&pw[(size_t)idx*WST + lane*4];
      float fv[3] = {0,0,0};
      #pragma unroll
      for (int r=0;r<3;r++){
        int i = lane + 64*r;
        if (i < 130) fv[r] = fin[(size_t)src*130 + i];
      }
      Y_FROM_VEC();

      WAVE_SYNC();   // WAR

      if (lane < PWL4) *(float4*)&pw_s[lane*4] = pwv;
      #pragma unroll
      for (int r=0;r<3;r++) if (rm[r] >= 0) f_s[rm[r]] = fv[r];

      #pragma unroll
      for (int rg=0;rg<GR;rg++){
        int g = lane + 64*rg;
        if (g < GTOTP){
          float ya  = gc1[rg] ? y1 : y4;
          float yb2 = gc1[rg] ? y2 : y5;
          float yc  = gc1[rg] ? y3 : y6;
          float t = cgr[rg][0]*ya + cgr[rg][1]*yb2 + cgr[rg][2]*yc + cgr[rg][3]*y7 + cgr[rg][4]*y8;
          G_s[g] = gc0[rg] ? cgr[rg][0] : t;
        }
      }

      WAVE_SYNC();   // RAW

      if (lane<32){
        mac_seg<1,1>(f_s,G_s,pw_s,md[0],&acc[0]);
        mac_seg<1,3>(f_s,G_s,pw_s,md[1],&acc[1]);
        mac_seg<1,5>(f_s,G_s,pw_s,md[2],&acc[4]);
      }
      if (lane<16) mac_seg<3,1>(f_s,G_s,pw_s,md[3],&acc[9]);
      if (lane<48) mac_seg<3,3>(f_s,G_s,pw_s,md[4],&acc[10]);
      if (lane<32) mac_seg<3,5>(f_s,G_s,pw_s,md[5],&acc[13]);
      if (lane<10) mac_seg<5,1>(f_s,G_s,pw_s,md[6],&acc[18]);
      if (lane<20) mac_seg<5,3>(f_s,G_s,pw_s,md[7],&acc[19]);
      if (lane<30) mac_seg<5,5>(f_s,G_s,pw_s,md[8],&acc[22]);
    }
  }

  // ---- epilogue ----
  WAVE_SYNC();
  constexpr float inv = 0.25f;
  if constexpr (LAYER==2){
    constexpr int RNKc[9] = {1,3,5,1,3,5,1,3,5};
    constexpr int AB[9]   = {0,1,4,9,10,13,18,19,22};
    constexpr int CNTc[9] = {32,32,32,16,48,32,10,20,30};
    constexpr int KSc[9]  = {0,100,96,0,100,96,0,100,96};
    #pragma unroll
    for (int r=0;r<9;r++){
      if (lane < CNTc[r]){
        #pragma unroll
        for (int k=0;k<RNKc[r];k++) row_s[cbs[r]+k*KSc[r]] = acc[AB[r]+k]*inv;
      }
    }
  } else if constexpr (LAYER==1){
    if (lane < 24){
      #pragma unroll
      for (int k=0;k<5;k++) if (k < l1nk) row_s[cbs[0]+k*8] = acc[k]*inv;
    }
  } else {
    if (lane < 58) row_s[cbs[0]] = acc[0]*inv;
  }
  WAVE_SYNC();

  const float* fo = fin + (size_t)n*FIN;   // own features (global)

  if constexpr (LAYER==3){
    float v = 0.f;
    if (lane < 58) v += row_s[lane]*linA[lane];
    if (lane < 32) v += fo[lane]*scA[lane];
    #pragma unroll
    for (int d=32; d>0; d>>=1) v += __shfl_down(v, d, 64);
    if (lane==0) outp[n] = v;
  } else {
    constexpr int NU0  = (LAYER==1) ? 8 : 58;
    constexpr int NSC0 = (LAYER==1) ? 8 : 32;
    if (lane < 32){
      float s = 0.f;
      for (int u=0;u<NU0;u++)  s += row_s[u]*linA[u*32+lane];
      for (int u=0;u<NSC0;u++) s += fo[u]*scA[u*32+lane];
      s0_s[lane] = s;
    }
    WAVE_SYNC();
    if (lane < 26){
      float s = 0.f;
      for (int v2=0;v2<32;v2++) s += s0_s[v2]*gw[v2*26+lane];
      g_s[lane] = 1.f/(1.f + __expf(-s));
    }
    WAVE_SYNC();
    for (int c=lane;c<130;c+=64){
      float val;
      if (c < 32){
        float s = s0_s[c];
        val = s/(1.f + __expf(-s));
      } else if (c < 80){
        int u = (c-32)/3, k = (c-32)%3;
        float s = 0.f;
        if constexpr (LAYER==1){
          const float4* rp = (const float4*)&row_s[8+k*8];
          float4 r0 = rp[0], r1 = rp[1];
          s = r0.x*linB[0*16+u]+r0.y*linB[1*16+u]+r0.z*linB[2*16+u]+r0.w*linB[3*16+u]
            + r1.x*linB[4*16+u]+r1.y*linB[5*16+u]+r1.z*linB[6*16+u]+r1.w*linB[7*16+u];
        } else {
          const float4* rp = (const float4*)&row_s[60+k*100];
          #pragma unroll 5
          for (int q=0;q<25;q++){
            float4 rv = rp[q];
            s += rv.x*linB[(4*q+0)*16+u] + rv.y*linB[(4*q+1)*16+u]
               + rv.z*linB[(4*q+2)*16+u] + rv.w*linB[(4*q+3)*16+u];
          }
          for (int up=0;up<16;up++) s += fo[32+up*3+k]*scB[up*16+u];
        }
        val = s*g_s[u];
      } else {
        int u = (c-80)/5, k = (c-80)%5;
        float s = 0.f;
        if constexpr (LAYER==1){
          const float4* rp = (const float4*)&row_s[32+k*8];
          float4 r0 = rp[0], r1 = rp[1];
          s = r0.x*linC[0*10+u]+r0.y*linC[1*10+u]+r0.z*linC[2*10+u]+r0.w*linC[3*10+u]
            + r1.x*linC[4*10+u]+r1.y*linC[5*10+u]+r1.z*linC[6*10+u]+r1.w*linC[7*10+u];
        } else {
          const float4* rp = (const float4*)&row_s[360+k*96];
          #pragma unroll 5
          for (int q=0;q<23;q++){
            float4 rv = rp[q];
            s += rv.x*linC[(4*q+0)*10+u] + rv.y*linC[(4*q+1)*10+u]
               + rv.z*linC[(4*q+2)*10+u] + rv.w*linC[(4*q+3)*10+u];
          }
          s += row_s[360+k*96+92]*linC[92*10+u] + row_s[360+k*96+93]*linC[93*10+u];
          for (int up=0;up<10;up++) s += fo[80+up*5+k]*scC[up*10+u];
        }
        val = s*g_s[16+u];
      }
      outp[(size_t)n*130 + c] = val;
    }
  }
}

// ===========================================================================
extern "C" void kernel_launch(void* const* d_in, const int* in_sizes, int n_in,
                              void* d_out, int out_size, void* d_ws, size_t ws_size,
                              hipStream_t stream){
  (void)in_sizes; (void)n_in; (void)out_size; (void)ws_size;
  const float* x        = (const float*)d_in[0];
  const float* edge_vec = (const float*)d_in[1];
  const float* fc1_w1   = (const float*)d_in[2];
  const float* fc1_w2   = (const float*)d_in[3];
  const float* lin1_l0  = (const float*)d_in[4];
  const float* lin1_l1  = (const float*)d_in[5];
  const float* lin1_l2  = (const float*)d_in[6];
  const float* sc1_l0   = (const float*)d_in[7];
  const float* gate1_w  = (const float*)d_in[8];
  const float* fc2_w1   = (const float*)d_in[9];
  const float* fc2_w2   = (const float*)d_in[10];
  const float* lin2_l0  = (const float*)d_in[11];
  const float* lin2_l1  = (const float*)d_in[12];
  const float* lin2_l2  = (const float*)d_in[13];
  const float* sc2_l0   = (const float*)d_in[14];
  const float* sc2_l1   = (const float*)d_in[15];
  const float* sc2_l2   = (const float*)d_in[16];
  const float* gate2_w  = (const float*)d_in[17];
  const float* fc3_w1   = (const float*)d_in[18];
  const float* fc3_w2   = (const float*)d_in[19];
  const float* lin3_l0  = (const float*)d_in[20];
  const float* sc3_l0   = (const float*)d_in[21];
  const int* edge_src   = (const int*)d_in[22];
  const int* edge_dst   = (const int*)d_in[23];
  float* out = (float*)d_out;

  char* base = (char*)d_ws;
  size_t off = 0;
  auto carve = [&](size_t bytes)->char*{
    char* p = base + off;
    off = (off + bytes + 255) & ~(size_t)255;
    return p;
  };
  int*   deg      = (int*)  carve((size_t)N_NODES*4);
  int*   offs     = (int*)  carve((size_t)(N_NODES+1)*4);
  int*   cursor   = (int*)  carve((size_t)N_NODES*4);
  int*   eids     = (int*)  carve((size_t)N_EDGES*4);
  int*   pos      = (int*)  carve((size_t)N_EDGES*4);
  int*   src_perm = (int*)  carve((size_t)N_EDGES*4);
  float* vec_perm = (float*)carve((size_t)N_EDGES*12);
  float* cgbuf    = (float*)carve(615*4);
  int*   nodeperm = (int*)  carve((size_t)N_NODES*4);
  float* hfeats   = (float*)carve((size_t)N_NODES*130*4);
  float* h2feats  = (float*)carve((size_t)N_NODES*130*4);
  float* pwbuf    = (float*)carve((size_t)N_EDGES*252*4);

  hipMemsetAsync(deg, 0, (size_t)N_NODES*4, stream);
  hist_kernel<<<N_EDGES/256, 256, 0, stream>>>(edge_dst, deg);
  scan_kernel<<<1, 1024, 0, stream>>>(deg, offs, cursor);
  scatter_kernel<<<N_EDGES/256, 256, 0, stream>>>(edge_dst, cursor, eids, pos);
  perm_kernel<<<N_EDGES/256, 256, 0, stream>>>(eids, edge_src, edge_vec, src_perm, vec_perm);
  nodesort_kernel<<<1, 1024, 0, stream>>>(deg, nodeperm);
  cg_init_kernel<<<15, 128, 0, stream>>>(cgbuf);

  mlp_kernel<24,24><<<N_EDGES/64, 256, 0, stream>>>(edge_vec, fc1_w1, fc1_w2, pos, pwbuf);
  conv_kernel<1><<<(N_NODES+3)/4, 256, 0, stream>>>(offs, nodeperm, src_perm, vec_perm, cgbuf, pwbuf,
      x, lin1_l0, lin1_l1, lin1_l2, sc1_l0, nullptr, nullptr, gate1_w, hfeats);
  mlp_kernel<252,252><<<N_EDGES/64, 256, 0, stream>>>(edge_vec, fc2_w1, fc2_w2, pos, pwbuf);
  conv_kernel<2><<<(N_NODES+3)/4, 256, 0, stream>>>(offs, nodeperm, src_perm, vec_perm, cgbuf, pwbuf,
      hfeats, lin2_l0, lin2_l1, lin2_l2, sc2_l0, sc2_l1, sc2_l2, gate2_w, h2feats);
  mlp_kernel<58,60><<<N_EDGES/64, 256, 0, stream>>>(edge_vec, fc3_w1, fc3_w2, pos, pwbuf);
  conv_kernel<3><<<(N_NODES+3)/4, 256, 0, stream>>>(offs, nodeperm, src_perm, vec_perm, cgbuf, pwbuf,
      h2feats, lin3_l0, nullptr, nullptr, sc3_l0, nullptr, nullptr, nullptr, out);
}